// Round 3
// baseline (606.317 us; speedup 1.0000x reference)
//
#include <hip/hip_runtime.h>

// Problem constants
#define NSEQ 512

// ---------------- GEMM1: x[4096,512] @ [Wq|Wk|Wv|Win][512,1600] + bias ----------------
// writes qs/ks/vs in [b*32+g][t][16] layout (g = c>>4) + hbuf Win part
// 128x128 tile, 8x8 micro, BK=8. grid (13, 32)
__global__ __launch_bounds__(256) void k_gemm1(
    const float* __restrict__ xb,
    const float* __restrict__ Wq, const float* __restrict__ Wk,
    const float* __restrict__ Wv, const float* __restrict__ Win,
    const float* __restrict__ bq, const float* __restrict__ bk_,
    const float* __restrict__ bv, const float* __restrict__ bin,
    float* __restrict__ qs, float* __restrict__ ks, float* __restrict__ vs,
    float* __restrict__ hbuf) {
  __shared__ __align__(16) float As[8][128];
  __shared__ __align__(16) float Bs[8][128];
  const int tid = threadIdx.x;
  const int tx = tid & 15, ty = tid >> 4;
  const int n0 = blockIdx.x * 128, m0 = blockIdx.y * 128;

  float acc[8][8];
#pragma unroll
  for (int i = 0; i < 8; ++i)
#pragma unroll
    for (int j = 0; j < 8; ++j) acc[i][j] = 0.f;

  const int am = tid >> 1, ak = (tid & 1) * 4;
  const int bkr = tid >> 5, bn = (tid & 31) * 4;
  const float* xptr = xb + (m0 + am) * 512 + ak;

  // select weight region for this thread's 4 B-columns (never straddles a 128-col tile... 
  // regions are 512/512/512/64, all multiples of 128 except Win tail handled by bvalid)
  const int c0 = n0 + bn;
  const float* Bw; int bcol; int ldb; bool bvalid;
  if (c0 < 512)       { Bw = Wq;  bcol = c0;        ldb = 512; bvalid = true; }
  else if (c0 < 1024) { Bw = Wk;  bcol = c0 - 512;  ldb = 512; bvalid = true; }
  else if (c0 < 1536) { Bw = Wv;  bcol = c0 - 1024; ldb = 512; bvalid = true; }
  else                { Bw = Win; bcol = c0 - 1536; ldb = 64;  bvalid = (c0 - 1536) < 64; }

  for (int k0 = 0; k0 < 512; k0 += 8) {
    float4 av = *(const float4*)(xptr + k0);
    float4 bvv = make_float4(0.f, 0.f, 0.f, 0.f);
    if (bvalid) bvv = *(const float4*)(Bw + (k0 + bkr) * ldb + bcol);
    __syncthreads();
    As[ak + 0][am] = av.x; As[ak + 1][am] = av.y;
    As[ak + 2][am] = av.z; As[ak + 3][am] = av.w;
    *(float4*)&Bs[bkr][bn] = bvv;
    __syncthreads();
#pragma unroll
    for (int kk = 0; kk < 8; ++kk) {
      float a[8], b[8];
      *(float4*)&a[0] = *(const float4*)&As[kk][ty * 8];
      *(float4*)&a[4] = *(const float4*)&As[kk][ty * 8 + 4];
      *(float4*)&b[0] = *(const float4*)&Bs[kk][tx * 8];
      *(float4*)&b[4] = *(const float4*)&Bs[kk][tx * 8 + 4];
#pragma unroll
      for (int i = 0; i < 8; ++i)
#pragma unroll
        for (int j = 0; j < 8; ++j) acc[i][j] += a[i] * b[j];
    }
  }
#pragma unroll
  for (int i = 0; i < 8; ++i) {
    int m = m0 + ty * 8 + i;
    int bb = m >> 9, t = m & 511;
#pragma unroll
    for (int j = 0; j < 8; ++j) {
      int c = n0 + tx * 8 + j;
      if (c >= 1600) continue;
      if (c < 512) {
        float v = acc[i][j] + bq[c];
        qs[(((bb << 5) + (c >> 4)) * 512 + t) * 16 + (c & 15)] = v * 0.25f;  // SCALE=HD^-0.5
      } else if (c < 1024) {
        int cc = c - 512;
        float v = acc[i][j] + bk_[cc];
        ks[(((bb << 5) + (cc >> 4)) * 512 + t) * 16 + (cc & 15)] = v;
      } else if (c < 1536) {
        int cc = c - 1024;
        float v = acc[i][j] + bv[cc];
        vs[(((bb << 5) + (cc >> 4)) * 512 + t) * 16 + (cc & 15)] = v;
      } else {
        int cc = c - 1536;
        if (cc < 64) {
          float v = acc[i][j] + bin[cc];
          hbuf[m * 576 + (cc >> 4) * 144 + 128 + (cc & 15)] = v;  // h[:, r, 128:144] = in_
        }
      }
    }
  }
}

// ---------------- attention: per (b,g) block; k,v in LDS; 2 rows/thread ----------------
__global__ __launch_bounds__(256) void k_attn(
    const float* __restrict__ qs, const float* __restrict__ ks,
    const float* __restrict__ vs, float* __restrict__ hbuf) {
  __shared__ __align__(16) float k_l[NSEQ * 16];   // 32 KB
  __shared__ __align__(16) float v_l[NSEQ * 16];   // 32 KB
  const int bg = blockIdx.x, tid = threadIdx.x;
  const float4* kg = (const float4*)(ks + bg * (NSEQ * 16));
  const float4* vg = (const float4*)(vs + bg * (NSEQ * 16));
  float4* k4 = (float4*)k_l;
  float4* v4 = (float4*)v_l;
  for (int idx = tid; idx < NSEQ * 4; idx += 256) {
    k4[idx] = kg[idx];
    v4[idx] = vg[idx];
  }
  const int i0 = tid, i1 = tid + 256;
  float q0[16], q1[16];
  const float* qp0 = qs + (bg * NSEQ + i0) * 16;
  const float* qp1 = qs + (bg * NSEQ + i1) * 16;
#pragma unroll
  for (int d = 0; d < 16; d += 4) {
    *(float4*)&q0[d] = *(const float4*)(qp0 + d);
    *(float4*)&q1[d] = *(const float4*)(qp1 + d);
  }
  float l0 = 0.f, l1 = 0.f;
  float o0[16], o1[16];
#pragma unroll
  for (int d = 0; d < 16; ++d) { o0[d] = 0.f; o1[d] = 0.f; }
  __syncthreads();

  for (int j = 0; j < NSEQ; ++j) {
    float kv[16];
#pragma unroll
    for (int d = 0; d < 4; ++d) *(float4*)&kv[d * 4] = k4[j * 4 + d];
    float s0 = 0.f, s1 = 0.f;
#pragma unroll
    for (int d = 0; d < 16; ++d) { s0 += q0[d] * kv[d]; s1 += q1[d] * kv[d]; }
    // softmax is shift-invariant; scores are O(+-3) so f32 exp without max-sub is safe.
    // diagonal masked to -inf in ref -> exp=0 here
    float e0 = (j == i0) ? 0.f : __expf(s0);
    float e1 = (j == i1) ? 0.f : __expf(s1);
    l0 += e0; l1 += e1;
#pragma unroll
    for (int d = 0; d < 4; ++d) {
      float4 vv = v4[j * 4 + d];
      o0[d * 4 + 0] += e0 * vv.x; o0[d * 4 + 1] += e0 * vv.y;
      o0[d * 4 + 2] += e0 * vv.z; o0[d * 4 + 3] += e0 * vv.w;
      o1[d * 4 + 0] += e1 * vv.x; o1[d * 4 + 1] += e1 * vv.y;
      o1[d * 4 + 2] += e1 * vv.z; o1[d * 4 + 3] += e1 * vv.w;
    }
  }
  const int g = bg & 31, bb = bg >> 5;
  const int r = g >> 3, hh = g & 7;
  const float inv0 = 1.f / l0, inv1 = 1.f / l1;
  const int base0 = (bb * NSEQ + i0) * 576 + r * 144 + hh * 16;
  const int base1 = (bb * NSEQ + i1) * 576 + r * 144 + hh * 16;
#pragma unroll
  for (int d = 0; d < 16; ++d) {
    hbuf[base0 + d] = o0[d] * inv0;
    hbuf[base1 + d] = o1[d] * inv1;
  }
}

// ---------------- MLP1: h[4096,(r),144] @ W1[r][144,405] + b1, relu -> h1 ----------------
// grid (4, 32, 4): 128x128 tile, 8x8 micro, BK=8, K=144
__global__ __launch_bounds__(256) void k_mlp1(
    const float* __restrict__ hbuf, const float* __restrict__ W1,
    const float* __restrict__ b1, float* __restrict__ h1) {
  __shared__ __align__(16) float As[8][128];
  __shared__ __align__(16) float Bs[8][128];
  const int tid = threadIdx.x;
  const int tx = tid & 15, ty = tid >> 4;
  const int n0 = blockIdx.x * 128, m0 = blockIdx.y * 128, r = blockIdx.z;

  float acc[8][8];
#pragma unroll
  for (int i = 0; i < 8; ++i)
#pragma unroll
    for (int j = 0; j < 8; ++j) acc[i][j] = 0.f;

  const int am = tid >> 1, ak = (tid & 1) * 4;
  const int bkr = tid >> 5, bn = (tid & 31) * 4;
  const float* aptr = hbuf + (m0 + am) * 576 + r * 144 + ak;
  const float* W1r = W1 + r * (144 * 405);

  for (int k0 = 0; k0 < 144; k0 += 8) {
    float4 av = *(const float4*)(aptr + k0);
    float b4[4];
#pragma unroll
    for (int u = 0; u < 4; ++u) {
      int c = n0 + bn + u;
      b4[u] = (c < 405) ? W1r[(k0 + bkr) * 405 + c] : 0.f;  // 405 odd -> scalar loads
    }
    __syncthreads();
    As[ak + 0][am] = av.x; As[ak + 1][am] = av.y;
    As[ak + 2][am] = av.z; As[ak + 3][am] = av.w;
    Bs[bkr][bn + 0] = b4[0]; Bs[bkr][bn + 1] = b4[1];
    Bs[bkr][bn + 2] = b4[2]; Bs[bkr][bn + 3] = b4[3];
    __syncthreads();
#pragma unroll
    for (int kk = 0; kk < 8; ++kk) {
      float a[8], b[8];
      *(float4*)&a[0] = *(const float4*)&As[kk][ty * 8];
      *(float4*)&a[4] = *(const float4*)&As[kk][ty * 8 + 4];
      *(float4*)&b[0] = *(const float4*)&Bs[kk][tx * 8];
      *(float4*)&b[4] = *(const float4*)&Bs[kk][tx * 8 + 4];
#pragma unroll
      for (int i = 0; i < 8; ++i)
#pragma unroll
        for (int j = 0; j < 8; ++j) acc[i][j] += a[i] * b[j];
    }
  }
#pragma unroll
  for (int i = 0; i < 8; ++i) {
    int m = m0 + ty * 8 + i;
#pragma unroll
    for (int j = 0; j < 8; ++j) {
      int c = n0 + tx * 8 + j;
      if (c < 405) {
        float v = acc[i][j] + b1[r * 405 + c];
        h1[(m * 4 + r) * 405 + c] = fmaxf(v, 0.f);
      }
    }
  }
}

// ---------------- MLP2 + rule-sum: y = sum_r rs[m,r]*(h1[m,r,:] @ W2[r] + b2[r]) ----------------
// grid (8, 32): BM=128, BN=64, micro 8x4, BK=8, K=405 per rule
__global__ __launch_bounds__(256) void k_mlp2(
    const float* __restrict__ h1, const float* __restrict__ W2,
    const float* __restrict__ b2, const float* __restrict__ rsb,
    float* __restrict__ yout) {
  __shared__ __align__(16) float As[8][128];
  __shared__ __align__(16) float Bs[8][64];
  __shared__ float rs_l[128][4];
  const int tid = threadIdx.x;
  const int tx = tid & 15, ty = tid >> 4;
  const int n0 = blockIdx.x * 64, m0 = blockIdx.y * 128;

  for (int idx = tid; idx < 512; idx += 256)
    rs_l[idx >> 2][idx & 3] = rsb[(m0 + (idx >> 2)) * 4 + (idx & 3)];

  float accY[8][4];
#pragma unroll
  for (int i = 0; i < 8; ++i)
#pragma unroll
    for (int j = 0; j < 4; ++j) accY[i][j] = 0.f;

  const int am = tid >> 1, ak = (tid & 1) * 4;
  const int bkr = tid >> 5, bn = (tid & 31) * 2;

  for (int r = 0; r < 4; ++r) {
    float acc[8][4];
#pragma unroll
    for (int i = 0; i < 8; ++i)
#pragma unroll
      for (int j = 0; j < 4; ++j) acc[i][j] = 0.f;

    const float* h1p = h1 + ((m0 + am) * 4 + r) * 405;
    const float* W2r = W2 + r * (405 * 512);

    for (int k0 = 0; k0 < 405; k0 += 8) {
      float a4[4];
#pragma unroll
      for (int u = 0; u < 4; ++u) {
        int k = k0 + ak + u;
        a4[u] = (k < 405) ? h1p[k] : 0.f;
      }
      float2 bvv = make_float2(0.f, 0.f);
      int krow = k0 + bkr;
      if (krow < 405) bvv = *(const float2*)(W2r + krow * 512 + n0 + bn);
      __syncthreads();
      As[ak + 0][am] = a4[0]; As[ak + 1][am] = a4[1];
      As[ak + 2][am] = a4[2]; As[ak + 3][am] = a4[3];
      *(float2*)&Bs[bkr][bn] = bvv;
      __syncthreads();
#pragma unroll
      for (int kk = 0; kk < 8; ++kk) {
        float a[8], b[4];
        *(float4*)&a[0] = *(const float4*)&As[kk][ty * 8];
        *(float4*)&a[4] = *(const float4*)&As[kk][ty * 8 + 4];
        *(float4*)&b[0] = *(const float4*)&Bs[kk][tx * 4];
#pragma unroll
        for (int i = 0; i < 8; ++i)
#pragma unroll
          for (int j = 0; j < 4; ++j) acc[i][j] += a[i] * b[j];
      }
    }
#pragma unroll
    for (int i = 0; i < 8; ++i) {
      float sc = rs_l[ty * 8 + i][r];
#pragma unroll
      for (int j = 0; j < 4; ++j)
        accY[i][j] += sc * (acc[i][j] + b2[r * 512 + n0 + tx * 4 + j]);
    }
  }
#pragma unroll
  for (int i = 0; i < 8; ++i) {
    int m = m0 + ty * 8 + i;
#pragma unroll
    for (int j = 0; j < 4; ++j) {
      int c = n0 + tx * 4 + j;
      yout[m * 512 + c] = accY[i][j];
    }
  }
}

// ---------------- passthrough copy of r_scores (output 1) ----------------
__global__ void k_copy(const float* __restrict__ in, float* __restrict__ out, int n) {
  int i = blockIdx.x * 256 + threadIdx.x;
  if (i < n) out[i] = in[i];
}

extern "C" void kernel_launch(void* const* d_in, const int* in_sizes, int n_in,
                              void* d_out, int out_size, void* d_ws, size_t ws_size,
                              hipStream_t stream) {
  const float* x    = (const float*)d_in[0];
  const float* rs   = (const float*)d_in[1];
  const float* Wq   = (const float*)d_in[2];
  const float* bq   = (const float*)d_in[3];
  const float* Wk   = (const float*)d_in[4];
  const float* bk   = (const float*)d_in[5];
  const float* Wv   = (const float*)d_in[6];
  const float* bv   = (const float*)d_in[7];
  const float* Win  = (const float*)d_in[8];
  const float* bin  = (const float*)d_in[9];
  const float* W1   = (const float*)d_in[10];
  const float* b1   = (const float*)d_in[11];
  const float* W2   = (const float*)d_in[12];
  const float* b2   = (const float*)d_in[13];
  float* out = (float*)d_out;

  // workspace layout (36.0 MB): hbuf | union(q,k,v ; h1)
  // q/k/v are dead after k_attn, so h1 (26.5MB) aliases the q/k/v region (24MB) + tail
  float* hbuf = (float*)d_ws;            // 4096*576   = 2,359,296 f32
  float* qs   = hbuf + 2359296;          // 2,097,152 f32
  float* ks   = qs + 2097152;            // 2,097,152 f32
  float* vs   = ks + 2097152;            // 2,097,152 f32
  float* h1   = qs;                      // 4096*4*405 = 6,635,520 f32 (aliases q/k/v)

  k_gemm1<<<dim3(13, 32), 256, 0, stream>>>(x, Wq, Wk, Wv, Win, bq, bk, bv, bin,
                                            qs, ks, vs, hbuf);
  k_attn<<<256, 256, 0, stream>>>(qs, ks, vs, hbuf);
  k_mlp1<<<dim3(4, 32, 4), 256, 0, stream>>>(hbuf, W1, b1, h1);
  k_mlp2<<<dim3(8, 32), 256, 0, stream>>>(h1, W2, b2, rs, out);
  k_copy<<<64, 256, 0, stream>>>(rs, out + 2097152, 16384);
}

// Round 4
// 292.924 us; speedup vs baseline: 2.0699x; 2.0699x over previous
//
#include <hip/hip_runtime.h>

typedef unsigned short u16;
typedef __attribute__((ext_vector_type(8))) short bf16x8;
typedef __attribute__((ext_vector_type(4))) float f32x4;
typedef unsigned int u32;
typedef __attribute__((ext_vector_type(4))) u32 u32x4;

__device__ __forceinline__ float bf2f(u16 u) {
  return __uint_as_float(((u32)u) << 16);
}
__device__ __forceinline__ u16 f2bf(float f) {
  u32 x = __float_as_uint(f);
  return (u16)((x + 0x7fffu + ((x >> 16) & 1u)) >> 16);
}

// ============ prep: build bf16 operands, fold biases/scales ============
// xp  [4096][544]  : x | 1.0 | 0-pad                       (A of gemm1)
// Wt1 [1600][544]  : W^T | bias | 0-pad, q-cols pre-scaled (B^T of gemm1)
// W1t [4][448][160]: W1^T | b1-slot@144 | 0-pad (rows>=405 zero)
// W2t [512][1696]  : concat_r W2_r^T (405->416 pad) | b2 slots@1664+r | 0
// hbuf pad cols [144..160): 1.0 at 144, zeros after
#define PREP_XP    2228224
#define PREP_WT1   3098624   // +870400
#define PREP_W1T   3385344   // +286720
#define PREP_W2T   4253696   // +868352
#define PREP_TOT   4515840   // +262144 (hbuf pad)

__global__ void k_prep(const float* __restrict__ x,
                       const float* __restrict__ Wq, const float* __restrict__ bq,
                       const float* __restrict__ Wk, const float* __restrict__ bk,
                       const float* __restrict__ Wv, const float* __restrict__ bv,
                       const float* __restrict__ Win, const float* __restrict__ bin,
                       const float* __restrict__ W1, const float* __restrict__ b1,
                       const float* __restrict__ W2, const float* __restrict__ b2,
                       u16* __restrict__ xp, u16* __restrict__ Wt1,
                       u16* __restrict__ W1t, u16* __restrict__ W2t,
                       u16* __restrict__ hbuf) {
  int i = blockIdx.x * 256 + threadIdx.x;
  if (i < PREP_XP) {
    int m = i / 544, k = i % 544;
    float v = (k < 512) ? x[m * 512 + k] : (k == 512 ? 1.f : 0.f);
    xp[i] = f2bf(v);
  } else if (i < PREP_WT1) {
    int j = i - PREP_XP;
    int c = j / 544, k = j % 544;
    float v;
    if (k < 512) {
      if (c < 512)        v = Wq[k * 512 + c];
      else if (c < 1024)  v = Wk[k * 512 + (c - 512)];
      else if (c < 1536)  v = Wv[k * 512 + (c - 1024)];
      else                v = Win[k * 64 + (c - 1536)];
    } else if (k == 512) {
      if (c < 512)        v = bq[c];
      else if (c < 1024)  v = bk[c - 512];
      else if (c < 1536)  v = bv[c - 1024];
      else                v = bin[c - 1536];
    } else v = 0.f;
    if (c < 512) v *= 0.25f;   // SCALE = HD^-0.5
    Wt1[j] = f2bf(v);
  } else if (i < PREP_W1T) {
    int j = i - PREP_WT1;
    int r = j / 71680, rem = j % 71680;   // 448*160
    int e = rem / 160, d = rem % 160;
    float v = 0.f;
    if (e < 405) {
      if (d < 144)      v = W1[(r * 144 + d) * 405 + e];
      else if (d == 144) v = b1[r * 405 + e];
    }
    W1t[j] = f2bf(v);
  } else if (i < PREP_W2T) {
    int j = i - PREP_W1T;
    int c = j / 1696, k = j % 1696;
    float v = 0.f;
    if (k < 1664) {
      int r = k / 416, e = k % 416;
      if (e < 405) v = W2[(r * 405 + e) * 512 + c];
    } else if (k < 1668) {
      v = b2[(k - 1664) * 512 + c];
    }
    W2t[j] = f2bf(v);
  } else if (i < PREP_TOT) {
    int j = i - PREP_W2T;
    int mr = j >> 4, d = j & 15;
    hbuf[mr * 160 + 144 + d] = f2bf(d == 0 ? 1.f : 0.f);
  }
}

// ============ shared MFMA core: 128x64 tile, 4 waves (2x2), K-step 32 ============
// A row-major [M][ldA] bf16, B given TRANSPOSED [N][ldB] bf16 (rows = out cols).
// LDS stride 40 bf16 (+8 pad -> 2-way bank aliasing only).
__device__ __forceinline__ void mfma_block128(
    const u16* __restrict__ Ag, int ldA,
    const u16* __restrict__ Bg, int ldB,
    int nstep, f32x4 (&acc)[4][2]) {
  __shared__ u16 Al[128][40];
  __shared__ u16 Bl[64][40];
  const int tid = threadIdx.x;
  const int lane = tid & 63;
  const int wr = (tid >> 7) & 1, wc = (tid >> 6) & 1;
  const int lrow = lane & 15, lk = (lane >> 4) * 8;

  const int ar0 = tid >> 2;            // 0..63
  const int aseg = (tid & 3) * 8;      // 0/8/16/24 (bf16 elems)
  const u16* Ap0 = Ag + (size_t)ar0 * ldA + aseg;
  const u16* Ap1 = Ag + (size_t)(ar0 + 64) * ldA + aseg;
  const u16* Bp  = Bg + (size_t)ar0 * ldB + aseg;

  for (int s = 0; s < nstep; ++s) {
    const int k0 = s * 32;
    u32x4 a0 = *(const u32x4*)(Ap0 + k0);
    u32x4 a1 = *(const u32x4*)(Ap1 + k0);
    u32x4 b0 = *(const u32x4*)(Bp + k0);
    __syncthreads();
    *(u32x4*)&Al[ar0][aseg]      = a0;
    *(u32x4*)&Al[ar0 + 64][aseg] = a1;
    *(u32x4*)&Bl[ar0][aseg]      = b0;
    __syncthreads();
    bf16x8 af[4], bf[2];
#pragma unroll
    for (int fm = 0; fm < 4; ++fm)
      af[fm] = *(const bf16x8*)&Al[wr * 64 + fm * 16 + lrow][lk];
#pragma unroll
    for (int fn = 0; fn < 2; ++fn)
      bf[fn] = *(const bf16x8*)&Bl[wc * 32 + fn * 16 + lrow][lk];
#pragma unroll
    for (int fm = 0; fm < 4; ++fm)
#pragma unroll
      for (int fn = 0; fn < 2; ++fn)
        acc[fm][fn] = __builtin_amdgcn_mfma_f32_16x16x32_bf16(
            af[fm], bf[fn], acc[fm][fn], 0, 0, 0);
  }
}

// ============ GEMM1: xp[4096,544] @ Wt1^T -> qs/ks/vs f32 + hbuf Win part ============
// grid (25, 32)
__global__ __launch_bounds__(256) void k_gemm1(
    const u16* __restrict__ xp, const u16* __restrict__ Wt1,
    float* __restrict__ qs, float* __restrict__ ks, float* __restrict__ vs,
    u16* __restrict__ hbuf) {
  f32x4 acc[4][2];
#pragma unroll
  for (int a = 0; a < 4; ++a)
#pragma unroll
    for (int b = 0; b < 2; ++b) acc[a][b] = (f32x4){0.f, 0.f, 0.f, 0.f};
  const int n0 = blockIdx.x * 64, m0 = blockIdx.y * 128;
  mfma_block128(xp + (size_t)m0 * 544, 544, Wt1 + (size_t)n0 * 544, 544, 17, acc);

  const int lane = threadIdx.x & 63;
  const int wr = (threadIdx.x >> 7) & 1, wc = (threadIdx.x >> 6) & 1;
  const int rr = (lane >> 4) * 4, cl = lane & 15;
#pragma unroll
  for (int fm = 0; fm < 4; ++fm) {
#pragma unroll
    for (int i = 0; i < 4; ++i) {
      int m = m0 + wr * 64 + fm * 16 + rr + i;
      int bb = m >> 9, t = m & 511;
#pragma unroll
      for (int fn = 0; fn < 2; ++fn) {
        int c = n0 + wc * 32 + fn * 16 + cl;
        float v = acc[fm][fn][i];
        if (c < 512) {
          qs[(((bb << 5) + (c >> 4)) * 512 + t) * 16 + (c & 15)] = v;
        } else if (c < 1024) {
          int q2 = c - 512;
          ks[(((bb << 5) + (q2 >> 4)) * 512 + t) * 16 + (q2 & 15)] = v;
        } else if (c < 1536) {
          int q2 = c - 1024;
          vs[(((bb << 5) + (q2 >> 4)) * 512 + t) * 16 + (q2 & 15)] = v;
        } else {
          int q2 = c - 1536;
          hbuf[(m * 4 + (q2 >> 4)) * 160 + 128 + (q2 & 15)] = f2bf(v);
        }
      }
    }
  }
}

// ============ attention: per (b,g) block; k,v f32 in LDS; 2 rows/thread ============
__global__ __launch_bounds__(256) void k_attn(
    const float* __restrict__ qs, const float* __restrict__ ks,
    const float* __restrict__ vs, u16* __restrict__ hbuf) {
  __shared__ __align__(16) float k_l[512 * 16];
  __shared__ __align__(16) float v_l[512 * 16];
  const int bg = blockIdx.x, tid = threadIdx.x;
  const float4* kg = (const float4*)(ks + bg * (512 * 16));
  const float4* vg = (const float4*)(vs + bg * (512 * 16));
  float4* k4 = (float4*)k_l;
  float4* v4 = (float4*)v_l;
  for (int idx = tid; idx < 512 * 4; idx += 256) {
    k4[idx] = kg[idx];
    v4[idx] = vg[idx];
  }
  const int i0 = tid, i1 = tid + 256;
  float q0[16], q1[16];
  const float* qp0 = qs + (bg * 512 + i0) * 16;
  const float* qp1 = qs + (bg * 512 + i1) * 16;
#pragma unroll
  for (int d = 0; d < 16; d += 4) {
    *(float4*)&q0[d] = *(const float4*)(qp0 + d);
    *(float4*)&q1[d] = *(const float4*)(qp1 + d);
  }
  float l0 = 0.f, l1 = 0.f;
  float o0[16], o1[16];
#pragma unroll
  for (int d = 0; d < 16; ++d) { o0[d] = 0.f; o1[d] = 0.f; }
  __syncthreads();

  for (int j = 0; j < 512; ++j) {
    float kv[16];
#pragma unroll
    for (int d = 0; d < 4; ++d) *(float4*)&kv[d * 4] = k4[j * 4 + d];
    float s0 = 0.f, s1 = 0.f;
#pragma unroll
    for (int d = 0; d < 16; ++d) { s0 += q0[d] * kv[d]; s1 += q1[d] * kv[d]; }
    float e0 = (j == i0) ? 0.f : __expf(s0);
    float e1 = (j == i1) ? 0.f : __expf(s1);
    l0 += e0; l1 += e1;
#pragma unroll
    for (int d = 0; d < 4; ++d) {
      float4 vv = v4[j * 4 + d];
      o0[d * 4 + 0] += e0 * vv.x; o0[d * 4 + 1] += e0 * vv.y;
      o0[d * 4 + 2] += e0 * vv.z; o0[d * 4 + 3] += e0 * vv.w;
      o1[d * 4 + 0] += e1 * vv.x; o1[d * 4 + 1] += e1 * vv.y;
      o1[d * 4 + 2] += e1 * vv.z; o1[d * 4 + 3] += e1 * vv.w;
    }
  }
  const int g = bg & 31, bb = bg >> 5;
  const int r = g >> 3, hh = g & 7;
  const float inv0 = 1.f / l0, inv1 = 1.f / l1;
  const int base0 = ((bb * 512 + i0) * 4 + r) * 160 + hh * 16;
  const int base1 = ((bb * 512 + i1) * 4 + r) * 160 + hh * 16;
#pragma unroll
  for (int d = 0; d < 16; ++d) {
    hbuf[base0 + d] = f2bf(o0[d] * inv0);
    hbuf[base1 + d] = f2bf(o1[d] * inv1);
  }
}

// ============ MLP1: hbuf[m][r][160] @ W1t[r] -> h1 (relu, *rs, bf16) ============
// grid (7, 32, 4); writes h1[m][r*416+e] for e<416; bx==6 blocks also fill rs slots
__global__ __launch_bounds__(256) void k_mlp1(
    const u16* __restrict__ hbuf, const u16* __restrict__ W1t,
    const float* __restrict__ rsb, u16* __restrict__ h1) {
  f32x4 acc[4][2];
#pragma unroll
  for (int a = 0; a < 4; ++a)
#pragma unroll
    for (int b = 0; b < 2; ++b) acc[a][b] = (f32x4){0.f, 0.f, 0.f, 0.f};
  const int n0 = blockIdx.x * 64, m0 = blockIdx.y * 128, r = blockIdx.z;
  mfma_block128(hbuf + (size_t)m0 * 640 + r * 160, 640,
                W1t + (size_t)(r * 448 + n0) * 160, 160, 5, acc);

  const int lane = threadIdx.x & 63;
  const int wr = (threadIdx.x >> 7) & 1, wc = (threadIdx.x >> 6) & 1;
  const int rr = (lane >> 4) * 4, cl = lane & 15;
#pragma unroll
  for (int fm = 0; fm < 4; ++fm) {
#pragma unroll
    for (int i = 0; i < 4; ++i) {
      int m = m0 + wr * 64 + fm * 16 + rr + i;
      float rsv = rsb[m * 4 + r];
#pragma unroll
      for (int fn = 0; fn < 2; ++fn) {
        int e = n0 + wc * 32 + fn * 16 + cl;
        if (e < 416)
          h1[(size_t)m * 1696 + r * 416 + e] = f2bf(rsv * fmaxf(acc[fm][fn][i], 0.f));
      }
    }
  }
  // rs slots + tail zeros (K pad region of mlp2's A)
  if (blockIdx.x == 6 && threadIdx.x < 128) {
    int m = m0 + threadIdx.x;
    h1[(size_t)m * 1696 + 1664 + r] = f2bf(rsb[m * 4 + r]);
    if (r == 0)
      for (int z = 1668; z < 1696; ++z) h1[(size_t)m * 1696 + z] = 0;
  }
}

// ============ MLP2: h1[4096,1696] @ W2t^T -> y f32 (bias & rs folded) ============
// grid (8, 32)
__global__ __launch_bounds__(256) void k_mlp2(
    const u16* __restrict__ h1, const u16* __restrict__ W2t,
    float* __restrict__ yout) {
  f32x4 acc[4][2];
#pragma unroll
  for (int a = 0; a < 4; ++a)
#pragma unroll
    for (int b = 0; b < 2; ++b) acc[a][b] = (f32x4){0.f, 0.f, 0.f, 0.f};
  const int n0 = blockIdx.x * 64, m0 = blockIdx.y * 128;
  mfma_block128(h1 + (size_t)m0 * 1696, 1696, W2t + (size_t)n0 * 1696, 1696, 53, acc);

  const int lane = threadIdx.x & 63;
  const int wr = (threadIdx.x >> 7) & 1, wc = (threadIdx.x >> 6) & 1;
  const int rr = (lane >> 4) * 4, cl = lane & 15;
#pragma unroll
  for (int fm = 0; fm < 4; ++fm) {
#pragma unroll
    for (int i = 0; i < 4; ++i) {
      int m = m0 + wr * 64 + fm * 16 + rr + i;
#pragma unroll
      for (int fn = 0; fn < 2; ++fn) {
        int c = n0 + wc * 32 + fn * 16 + cl;
        yout[(size_t)m * 512 + c] = acc[fm][fn][i];
      }
    }
  }
}

// ============ passthrough copy of r_scores (output 1) ============
__global__ void k_copy(const float* __restrict__ in, float* __restrict__ out, int n) {
  int i = blockIdx.x * 256 + threadIdx.x;
  if (i < n) out[i] = in[i];
}

extern "C" void kernel_launch(void* const* d_in, const int* in_sizes, int n_in,
                              void* d_out, int out_size, void* d_ws, size_t ws_size,
                              hipStream_t stream) {
  const float* x    = (const float*)d_in[0];
  const float* rs   = (const float*)d_in[1];
  const float* Wq   = (const float*)d_in[2];
  const float* bq   = (const float*)d_in[3];
  const float* Wk   = (const float*)d_in[4];
  const float* bk   = (const float*)d_in[5];
  const float* Wv   = (const float*)d_in[6];
  const float* bv   = (const float*)d_in[7];
  const float* Win  = (const float*)d_in[8];
  const float* bin  = (const float*)d_in[9];
  const float* W1   = (const float*)d_in[10];
  const float* b1   = (const float*)d_in[11];
  const float* W2   = (const float*)d_in[12];
  const float* b2   = (const float*)d_in[13];
  float* out = (float*)d_out;

  // ws layout (38.9 MB):
  // bf16: xp | Wt1 | W1t | W2t | hbuf ; then f32 qs/ks/vs (25.2MB)
  // h1 (13.9MB bf16) aliases qs region (q/k/v dead after k_attn)
  u16* xp   = (u16*)d_ws;             // 2,228,224
  u16* Wt1  = xp + 2228224;           //   870,400
  u16* W1t  = Wt1 + 870400;           //   286,720
  u16* W2t  = W1t + 286720;           //   868,352
  u16* hbuf = W2t + 868352;           // 2,621,440  (end: 6,875,136 u16, 16B-aligned)
  float* qs = (float*)(xp + 6875136); // 2,097,152 f32
  float* ks = qs + 2097152;
  float* vs = ks + 2097152;
  u16* h1   = (u16*)qs;               // 6,946,816 u16 (aliases qs/ks/vs)

  k_prep<<<(PREP_TOT + 255) / 256, 256, 0, stream>>>(
      x, Wq, bq, Wk, bk, Wv, bv, Win, bin, W1, b1, W2, b2,
      xp, Wt1, W1t, W2t, hbuf);
  k_gemm1<<<dim3(25, 32), 256, 0, stream>>>(xp, Wt1, qs, ks, vs, hbuf);
  k_attn<<<256, 256, 0, stream>>>(qs, ks, vs, hbuf);
  k_mlp1<<<dim3(7, 32, 4), 256, 0, stream>>>(hbuf, W1t, rs, h1);
  k_mlp2<<<dim3(8, 32), 256, 0, stream>>>(h1, W2t, out);
  k_copy<<<64, 256, 0, stream>>>(rs, out + 2097152, 16384);
}

// Round 5
// 208.503 us; speedup vs baseline: 2.9080x; 1.4049x over previous
//
#include <hip/hip_runtime.h>

typedef unsigned short u16;
typedef __attribute__((ext_vector_type(8))) short bf16x8;
typedef __attribute__((ext_vector_type(4))) float f32x4;
typedef unsigned int u32;
typedef __attribute__((ext_vector_type(4))) u32 u32x4;

__device__ __forceinline__ float bf2f(u16 u) {
  return __uint_as_float(((u32)u) << 16);
}
__device__ __forceinline__ u16 f2bf(float f) {
  u32 x = __float_as_uint(f);
  return (u16)((x + 0x7fffu + ((x >> 16) & 1u)) >> 16);
}
__device__ __forceinline__ u32 cvt_pk_bf16(float lo, float hi) {
  u32 r;
  asm("v_cvt_pk_bf16_f32 %0, %1, %2" : "=v"(r) : "v"(lo), "v"(hi));
  return r;
}

// ============ prep: build bf16 operands, fold biases/scales ============
#define PREP_XP    2228224
#define PREP_WT1   3098624   // +870400
#define PREP_W1T   3385344   // +286720
#define PREP_W2T   4253696   // +868352
#define PREP_TOT   4515840   // +262144 (hbuf pad)

__global__ void k_prep(const float* __restrict__ x,
                       const float* __restrict__ Wq, const float* __restrict__ bq,
                       const float* __restrict__ Wk, const float* __restrict__ bk,
                       const float* __restrict__ Wv, const float* __restrict__ bv,
                       const float* __restrict__ Win, const float* __restrict__ bin,
                       const float* __restrict__ W1, const float* __restrict__ b1,
                       const float* __restrict__ W2, const float* __restrict__ b2,
                       u16* __restrict__ xp, u16* __restrict__ Wt1,
                       u16* __restrict__ W1t, u16* __restrict__ W2t,
                       u16* __restrict__ hbuf) {
  int i = blockIdx.x * 256 + threadIdx.x;
  if (i < PREP_XP) {
    int m = i / 544, k = i % 544;
    float v = (k < 512) ? x[m * 512 + k] : (k == 512 ? 1.f : 0.f);
    xp[i] = f2bf(v);
  } else if (i < PREP_WT1) {
    int j = i - PREP_XP;
    int c = j / 544, k = j % 544;
    float v;
    if (k < 512) {
      if (c < 512)        v = Wq[k * 512 + c];
      else if (c < 1024)  v = Wk[k * 512 + (c - 512)];
      else if (c < 1536)  v = Wv[k * 512 + (c - 1024)];
      else                v = Win[k * 64 + (c - 1536)];
    } else if (k == 512) {
      if (c < 512)        v = bq[c];
      else if (c < 1024)  v = bk[c - 512];
      else if (c < 1536)  v = bv[c - 1024];
      else                v = bin[c - 1536];
    } else v = 0.f;
    if (c < 512) v *= 0.25f;   // SCALE = HD^-0.5
    Wt1[j] = f2bf(v);
  } else if (i < PREP_W1T) {
    int j = i - PREP_WT1;
    int r = j / 71680, rem = j % 71680;   // 448*160
    int e = rem / 160, d = rem % 160;
    float v = 0.f;
    if (e < 405) {
      if (d < 144)       v = W1[(r * 144 + d) * 405 + e];
      else if (d == 144) v = b1[r * 405 + e];
    }
    W1t[j] = f2bf(v);
  } else if (i < PREP_W2T) {
    int j = i - PREP_W1T;
    int c = j / 1696, k = j % 1696;
    float v = 0.f;
    if (k < 1664) {
      int r = k / 416, e = k % 416;
      if (e < 405) v = W2[(r * 405 + e) * 512 + c];
    } else if (k < 1668) {
      v = b2[(k - 1664) * 512 + c];
    }
    W2t[j] = f2bf(v);
  } else if (i < PREP_TOT) {
    int j = i - PREP_W2T;
    int mr = j >> 4, d = j & 15;
    hbuf[mr * 160 + 144 + d] = f2bf(d == 0 ? 1.f : 0.f);
  }
}

// ============ shared MFMA core: 128x64 tile, 4 waves (2x2), K-step 32 ============
__device__ __forceinline__ void mfma_block128(
    const u16* __restrict__ Ag, int ldA,
    const u16* __restrict__ Bg, int ldB,
    int nstep, f32x4 (&acc)[4][2]) {
  __shared__ u16 Al[128][40];
  __shared__ u16 Bl[64][40];
  const int tid = threadIdx.x;
  const int lane = tid & 63;
  const int wr = (tid >> 7) & 1, wc = (tid >> 6) & 1;
  const int lrow = lane & 15, lk = (lane >> 4) * 8;

  const int ar0 = tid >> 2;
  const int aseg = (tid & 3) * 8;
  const u16* Ap0 = Ag + (size_t)ar0 * ldA + aseg;
  const u16* Ap1 = Ag + (size_t)(ar0 + 64) * ldA + aseg;
  const u16* Bp  = Bg + (size_t)ar0 * ldB + aseg;

  for (int s = 0; s < nstep; ++s) {
    const int k0 = s * 32;
    u32x4 a0 = *(const u32x4*)(Ap0 + k0);
    u32x4 a1 = *(const u32x4*)(Ap1 + k0);
    u32x4 b0 = *(const u32x4*)(Bp + k0);
    __syncthreads();
    *(u32x4*)&Al[ar0][aseg]      = a0;
    *(u32x4*)&Al[ar0 + 64][aseg] = a1;
    *(u32x4*)&Bl[ar0][aseg]      = b0;
    __syncthreads();
    bf16x8 af[4], bf[2];
#pragma unroll
    for (int fm = 0; fm < 4; ++fm)
      af[fm] = *(const bf16x8*)&Al[wr * 64 + fm * 16 + lrow][lk];
#pragma unroll
    for (int fn = 0; fn < 2; ++fn)
      bf[fn] = *(const bf16x8*)&Bl[wc * 32 + fn * 16 + lrow][lk];
#pragma unroll
    for (int fm = 0; fm < 4; ++fm)
#pragma unroll
      for (int fn = 0; fn < 2; ++fn)
        acc[fm][fn] = __builtin_amdgcn_mfma_f32_16x16x32_bf16(
            af[fm], bf[fn], acc[fm][fn], 0, 0, 0);
  }
}

// ============ GEMM1: xp @ Wt1^T -> qb/kb bf16 [bg][t][16], vt bf16 [bg][16][512], hbuf ============
__global__ __launch_bounds__(256) void k_gemm1(
    const u16* __restrict__ xp, const u16* __restrict__ Wt1,
    u16* __restrict__ qb, u16* __restrict__ kb, u16* __restrict__ vt,
    u16* __restrict__ hbuf) {
  f32x4 acc[4][2];
#pragma unroll
  for (int a = 0; a < 4; ++a)
#pragma unroll
    for (int b = 0; b < 2; ++b) acc[a][b] = (f32x4){0.f, 0.f, 0.f, 0.f};
  const int n0 = blockIdx.x * 64, m0 = blockIdx.y * 128;
  mfma_block128(xp + (size_t)m0 * 544, 544, Wt1 + (size_t)n0 * 544, 544, 17, acc);

  const int lane = threadIdx.x & 63;
  const int wr = (threadIdx.x >> 7) & 1, wc = (threadIdx.x >> 6) & 1;
  const int rr = (lane >> 4) * 4, cl = lane & 15;
#pragma unroll
  for (int fm = 0; fm < 4; ++fm) {
#pragma unroll
    for (int i = 0; i < 4; ++i) {
      int m = m0 + wr * 64 + fm * 16 + rr + i;
      int bb = m >> 9, t = m & 511;
#pragma unroll
      for (int fn = 0; fn < 2; ++fn) {
        int c = n0 + wc * 32 + fn * 16 + cl;
        float v = acc[fm][fn][i];
        if (c < 512) {
          qb[((size_t)(((bb << 5) + (c >> 4)) * 512 + t)) * 16 + (c & 15)] = f2bf(v);
        } else if (c < 1024) {
          int q2 = c - 512;
          kb[((size_t)(((bb << 5) + (q2 >> 4)) * 512 + t)) * 16 + (q2 & 15)] = f2bf(v);
        } else if (c < 1536) {
          int q2 = c - 1024;
          vt[((size_t)(((bb << 5) + (q2 >> 4)) * 16 + (q2 & 15))) * 512 + t] = f2bf(v);
        } else {
          int q2 = c - 1536;
          hbuf[(m * 4 + (q2 >> 4)) * 160 + 128 + (q2 & 15)] = f2bf(v);
        }
      }
    }
  }
}

// ============ MFMA attention: per (b,g) block, 8 waves x 64 q-rows ============
// QK^T: mfma_16x16x32 (k 16..31 zeroed via exec-masked loads); no-max-sub softmax;
// P -> per-wave LDS (bf16) -> A-frag; PV: mfma_16x16x32 with V^T B-frags from global.
__global__ __launch_bounds__(512) void k_attn(
    const u16* __restrict__ qb, const u16* __restrict__ kb,
    const u16* __restrict__ vt, u16* __restrict__ hbuf) {
  __shared__ u16 P_lds[8][32][40];   // per-wave 32x32 P tile, stride 40 (80B, b128-aligned)
  const int bg = blockIdx.x;
  const int tid = threadIdx.x;
  const int w = tid >> 6, lane = tid & 63;
  const int cl = lane & 15, hq = lane >> 4;
  const int bb = bg >> 5, g = bg & 31, ru = g >> 3, hh = g & 7;
  const u16* qg = qb + (size_t)bg * 512 * 16;
  const u16* kg = kb + (size_t)bg * 512 * 16;
  const u16* vg = vt + (size_t)bg * 16 * 512;
  const bf16x8 zf = {0, 0, 0, 0, 0, 0, 0, 0};

#pragma unroll
  for (int s = 0; s < 2; ++s) {
    const int q0 = w * 64 + s * 32;
    bf16x8 qf[2];
#pragma unroll
    for (int rf = 0; rf < 2; ++rf) {
      qf[rf] = zf;
      if (hq < 2)
        qf[rf] = *(const bf16x8*)(qg + (size_t)(q0 + rf * 16 + cl) * 16 + hq * 8);
    }
    f32x4 oacc[2];
    oacc[0] = (f32x4){0.f, 0.f, 0.f, 0.f};
    oacc[1] = (f32x4){0.f, 0.f, 0.f, 0.f};
    float lsum[2][4] = {{0.f, 0.f, 0.f, 0.f}, {0.f, 0.f, 0.f, 0.f}};

    for (int c = 0; c < 16; ++c) {
      bf16x8 kf[2];
#pragma unroll
      for (int ch = 0; ch < 2; ++ch) {
        kf[ch] = zf;
        if (hq < 2)
          kf[ch] = *(const bf16x8*)(kg + (size_t)(c * 32 + ch * 16 + cl) * 16 + hq * 8);
      }
#pragma unroll
      for (int rf = 0; rf < 2; ++rf) {
#pragma unroll
        for (int ch = 0; ch < 2; ++ch) {
          f32x4 sv = __builtin_amdgcn_mfma_f32_16x16x32_bf16(
              qf[rf], kf[ch], (f32x4){0.f, 0.f, 0.f, 0.f}, 0, 0, 0);
          float e[4];
#pragma unroll
          for (int j = 0; j < 4; ++j) e[j] = __expf(sv[j]);
          if (q0 + rf * 16 == c * 32 + ch * 16) {   // diagonal sub-tile
#pragma unroll
            for (int j = 0; j < 4; ++j)
              if (hq * 4 + j == cl) e[j] = 0.f;
          }
#pragma unroll
          for (int j = 0; j < 4; ++j) lsum[rf][j] += e[j];
          u32 p01 = cvt_pk_bf16(e[0], e[1]);
          u32 p23 = cvt_pk_bf16(e[2], e[3]);
          const int prow = rf * 16 + hq * 4, pcol = ch * 16 + cl;
          P_lds[w][prow + 0][pcol] = (u16)p01;
          P_lds[w][prow + 1][pcol] = (u16)(p01 >> 16);
          P_lds[w][prow + 2][pcol] = (u16)p23;
          P_lds[w][prow + 3][pcol] = (u16)(p23 >> 16);
        }
      }
      // PV for this 32-col super-tile (per-wave LDS: waitcnt ordering only, no barrier)
      bf16x8 pa0 = *(const bf16x8*)&P_lds[w][cl][hq * 8];
      bf16x8 pa1 = *(const bf16x8*)&P_lds[w][16 + cl][hq * 8];
      bf16x8 vb = *(const bf16x8*)(vg + (size_t)cl * 512 + c * 32 + hq * 8);
      oacc[0] = __builtin_amdgcn_mfma_f32_16x16x32_bf16(pa0, vb, oacc[0], 0, 0, 0);
      oacc[1] = __builtin_amdgcn_mfma_f32_16x16x32_bf16(pa1, vb, oacc[1], 0, 0, 0);
    }
    // full row sums: reduce across the 16 lanes of each quad-column group
#pragma unroll
    for (int rf = 0; rf < 2; ++rf)
#pragma unroll
      for (int j = 0; j < 4; ++j) {
        float v = lsum[rf][j];
        v += __shfl_xor(v, 1);
        v += __shfl_xor(v, 2);
        v += __shfl_xor(v, 4);
        v += __shfl_xor(v, 8);
        lsum[rf][j] = v;
      }
    // normalize + write O (C/D row map of oacc == row map of lsum)
#pragma unroll
    for (int rf = 0; rf < 2; ++rf)
#pragma unroll
      for (int j = 0; j < 4; ++j) {
        int t = q0 + rf * 16 + hq * 4 + j;
        float val = oacc[rf][j] / lsum[rf][j];
        hbuf[((size_t)((bb * 512 + t) * 4 + ru)) * 160 + hh * 16 + cl] = f2bf(val);
      }
  }
}

// ============ MLP1: hbuf[m][r][160] @ W1t[r] -> h1 (relu, *rs, bf16) ============
__global__ __launch_bounds__(256) void k_mlp1(
    const u16* __restrict__ hbuf, const u16* __restrict__ W1t,
    const float* __restrict__ rsb, u16* __restrict__ h1) {
  f32x4 acc[4][2];
#pragma unroll
  for (int a = 0; a < 4; ++a)
#pragma unroll
    for (int b = 0; b < 2; ++b) acc[a][b] = (f32x4){0.f, 0.f, 0.f, 0.f};
  const int n0 = blockIdx.x * 64, m0 = blockIdx.y * 128, r = blockIdx.z;
  mfma_block128(hbuf + (size_t)m0 * 640 + r * 160, 640,
                W1t + (size_t)(r * 448 + n0) * 160, 160, 5, acc);

  const int lane = threadIdx.x & 63;
  const int wr = (threadIdx.x >> 7) & 1, wc = (threadIdx.x >> 6) & 1;
  const int rr = (lane >> 4) * 4, cl = lane & 15;
#pragma unroll
  for (int fm = 0; fm < 4; ++fm) {
#pragma unroll
    for (int i = 0; i < 4; ++i) {
      int m = m0 + wr * 64 + fm * 16 + rr + i;
      float rsv = rsb[m * 4 + r];
#pragma unroll
      for (int fn = 0; fn < 2; ++fn) {
        int e = n0 + wc * 32 + fn * 16 + cl;
        if (e < 416)
          h1[(size_t)m * 1696 + r * 416 + e] = f2bf(rsv * fmaxf(acc[fm][fn][i], 0.f));
      }
    }
  }
  if (blockIdx.x == 6 && threadIdx.x < 128) {
    int m = m0 + threadIdx.x;
    h1[(size_t)m * 1696 + 1664 + r] = f2bf(rsb[m * 4 + r]);
    if (r == 0)
      for (int z = 1668; z < 1696; ++z) h1[(size_t)m * 1696 + z] = 0;
  }
}

// ============ MLP2: h1[4096,1696] @ W2t^T -> y f32 (bias & rs folded) ============
__global__ __launch_bounds__(256) void k_mlp2(
    const u16* __restrict__ h1, const u16* __restrict__ W2t,
    float* __restrict__ yout) {
  f32x4 acc[4][2];
#pragma unroll
  for (int a = 0; a < 4; ++a)
#pragma unroll
    for (int b = 0; b < 2; ++b) acc[a][b] = (f32x4){0.f, 0.f, 0.f, 0.f};
  const int n0 = blockIdx.x * 64, m0 = blockIdx.y * 128;
  mfma_block128(h1 + (size_t)m0 * 1696, 1696, W2t + (size_t)n0 * 1696, 1696, 53, acc);

  const int lane = threadIdx.x & 63;
  const int wr = (threadIdx.x >> 7) & 1, wc = (threadIdx.x >> 6) & 1;
  const int rr = (lane >> 4) * 4, cl = lane & 15;
#pragma unroll
  for (int fm = 0; fm < 4; ++fm) {
#pragma unroll
    for (int i = 0; i < 4; ++i) {
      int m = m0 + wr * 64 + fm * 16 + rr + i;
#pragma unroll
      for (int fn = 0; fn < 2; ++fn) {
        int c = n0 + wc * 32 + fn * 16 + cl;
        yout[(size_t)m * 512 + c] = acc[fm][fn][i];
      }
    }
  }
}

// ============ passthrough copy of r_scores (output 1) ============
__global__ void k_copy(const float* __restrict__ in, float* __restrict__ out, int n) {
  int i = blockIdx.x * 256 + threadIdx.x;
  if (i < n) out[i] = in[i];
}

extern "C" void kernel_launch(void* const* d_in, const int* in_sizes, int n_in,
                              void* d_out, int out_size, void* d_ws, size_t ws_size,
                              hipStream_t stream) {
  const float* x    = (const float*)d_in[0];
  const float* rs   = (const float*)d_in[1];
  const float* Wq   = (const float*)d_in[2];
  const float* bq   = (const float*)d_in[3];
  const float* Wk   = (const float*)d_in[4];
  const float* bk   = (const float*)d_in[5];
  const float* Wv   = (const float*)d_in[6];
  const float* bv   = (const float*)d_in[7];
  const float* Win  = (const float*)d_in[8];
  const float* bin  = (const float*)d_in[9];
  const float* W1   = (const float*)d_in[10];
  const float* b1   = (const float*)d_in[11];
  const float* W2   = (const float*)d_in[12];
  const float* b2   = (const float*)d_in[13];
  float* out = (float*)d_out;

  // ws layout (27.6 MB), all bf16:
  // xp | Wt1 | W1t | W2t | hbuf | qb | kb | vt ; h1 aliases qb..vt+tail
  u16* xp   = (u16*)d_ws;             // 2,228,224
  u16* Wt1  = xp + 2228224;           //   870,400
  u16* W1t  = Wt1 + 870400;           //   286,720
  u16* W2t  = W1t + 286720;           //   868,352
  u16* hbuf = W2t + 868352;           // 2,621,440
  u16* qb   = hbuf + 2621440;         // 2,097,152
  u16* kb   = qb + 2097152;           // 2,097,152
  u16* vt   = kb + 2097152;           // 2,097,152
  u16* h1   = qb;                     // 6,946,816 (aliases qb/kb/vt; q/k/v dead after attn)

  k_prep<<<(PREP_TOT + 255) / 256, 256, 0, stream>>>(
      x, Wq, bq, Wk, bk, Wv, bv, Win, bin, W1, b1, W2, b2,
      xp, Wt1, W1t, W2t, hbuf);
  k_gemm1<<<dim3(25, 32), 256, 0, stream>>>(xp, Wt1, qb, kb, vt, hbuf);
  k_attn<<<256, 512, 0, stream>>>(qb, kb, vt, hbuf);
  k_mlp1<<<dim3(7, 32, 4), 256, 0, stream>>>(hbuf, W1t, rs, h1);
  k_mlp2<<<dim3(8, 32), 256, 0, stream>>>(h1, W2t, out);
  k_copy<<<64, 256, 0, stream>>>(rs, out + 2097152, 16384);
}

// Round 7
// 199.834 us; speedup vs baseline: 3.0341x; 1.0434x over previous
//
#include <hip/hip_runtime.h>

typedef unsigned short u16;
typedef __attribute__((ext_vector_type(8))) short bf16x8;
typedef __attribute__((ext_vector_type(4))) float f32x4;
typedef __attribute__((ext_vector_type(16))) float f32x16;
typedef unsigned int u32;
typedef __attribute__((ext_vector_type(2))) u32 u32x2;
typedef __attribute__((ext_vector_type(4))) u32 u32x4;

__device__ __forceinline__ u16 f2bf(float f) {
  u32 x = __float_as_uint(f);
  return (u16)((x + 0x7fffu + ((x >> 16) & 1u)) >> 16);
}
__device__ __forceinline__ u32 cvt_pk_bf16(float lo, float hi) {
  u32 r;
  asm("v_cvt_pk_bf16_f32 %0, %1, %2" : "=v"(r) : "v"(lo), "v"(hi));
  return r;
}

// ===================== prep kernels (coalesced) =====================
// misc: xp build (coalesced), W2t bias cols, hbuf pad, r_scores passthrough
#define MISC_XP   2228224                  // 4096*544
#define MISC_W2B  (MISC_XP + 512*32)       // + 16384
#define MISC_HB   (MISC_W2B + 262144)      // hbuf pad region
#define MISC_RS   (MISC_HB + 16384)        // rs passthrough
__global__ void k_prep_misc(const float* __restrict__ x, const float* __restrict__ b2,
                            const float* __restrict__ rs,
                            u16* __restrict__ xp, u16* __restrict__ W2t,
                            u16* __restrict__ hbuf, float* __restrict__ out) {
  int i = blockIdx.x * 256 + threadIdx.x;
  if (i < MISC_XP) {
    int m = i / 544, k = i % 544;
    float v = (k < 512) ? x[m * 512 + k] : (k == 512 ? 1.f : 0.f);
    xp[i] = f2bf(v);
  } else if (i < MISC_W2B) {
    int j = i - MISC_XP;
    int c = j >> 5, kk = j & 31;
    W2t[(size_t)c * 1696 + 1664 + kk] = (kk < 4) ? f2bf(b2[kk * 512 + c]) : (u16)0;
  } else if (i < MISC_HB) {
    int j = i - MISC_W2B;
    int mr = j >> 4, d = j & 15;
    hbuf[mr * 160 + 144 + d] = f2bf(d == 0 ? 1.f : 0.f);
  } else if (i < MISC_RS) {
    int j = i - MISC_HB;
    out[2097152 + j] = rs[j];
  }
}

// Wt1 [1600][544] = [Wq|Wk|Wv|Win]^T with bias row @k=512, q-cols scaled. LDS transpose.
__global__ __launch_bounds__(256) void k_prep_wt1(
    const float* __restrict__ Wq, const float* __restrict__ Wk,
    const float* __restrict__ Wv, const float* __restrict__ Win,
    const float* __restrict__ bq, const float* __restrict__ bk,
    const float* __restrict__ bv, const float* __restrict__ bin,
    u16* __restrict__ Wt1) {
  __shared__ float T[32][33];
  const int tx = threadIdx.x & 31, ty0 = threadIdx.x >> 5;
  const int k0 = blockIdx.y * 32, c0 = blockIdx.x * 32;
  const float* W; const float* bias; int ldc, cbase, cmax;
  if (c0 < 512)       { W = Wq;  bias = bq;  ldc = 512; cbase = 0;    cmax = 512; }
  else if (c0 < 1024) { W = Wk;  bias = bk;  ldc = 512; cbase = 512;  cmax = 512; }
  else if (c0 < 1536) { W = Wv;  bias = bv;  ldc = 512; cbase = 1024; cmax = 512; }
  else                { W = Win; bias = bin; ldc = 64;  cbase = 1536; cmax = 64;  }
  const int cc = c0 - cbase + tx;
#pragma unroll
  for (int rr = 0; rr < 4; ++rr) {
    int k = k0 + ty0 + rr * 8;
    float v = 0.f;
    if (cc < cmax) {
      if (k < 512)       v = W[k * ldc + cc];
      else if (k == 512) v = bias[cc];
    }
    T[ty0 + rr * 8][tx] = v;
  }
  __syncthreads();
  const float scale = (c0 < 512) ? 0.25f : 1.f;   // SCALE = HD^-0.5
#pragma unroll
  for (int rr = 0; rr < 4; ++rr) {
    int c = c0 + ty0 + rr * 8;
    int k = k0 + tx;
    Wt1[(size_t)c * 544 + k] = f2bf(T[tx][ty0 + rr * 8] * scale);
  }
}

// W1t [4][448][160]: W1^T (d<->e), b1 slot @d=144, zero pads. LDS transpose.
__global__ __launch_bounds__(256) void k_prep_w1t(
    const float* __restrict__ W1, const float* __restrict__ b1,
    u16* __restrict__ W1t) {
  __shared__ float T[32][33];
  const int tx = threadIdx.x & 31, ty0 = threadIdx.x >> 5;
  const int d0 = blockIdx.x * 32, e0 = blockIdx.y * 32, r = blockIdx.z;
#pragma unroll
  for (int rr = 0; rr < 4; ++rr) {
    int d = d0 + ty0 + rr * 8, e = e0 + tx;
    float v = 0.f;
    if (e < 405) {
      if (d < 144)       v = W1[(r * 144 + d) * 405 + e];
      else if (d == 144) v = b1[r * 405 + e];
    }
    T[ty0 + rr * 8][tx] = v;
  }
  __syncthreads();
#pragma unroll
  for (int rr = 0; rr < 4; ++rr) {
    int e = e0 + ty0 + rr * 8, d = d0 + tx;
    W1t[(size_t)r * 71680 + e * 160 + d] = f2bf(T[tx][ty0 + rr * 8]);
  }
}

// W2t [512][1696]: per-rule W2^T (e<->c), e padded 405->416. LDS transpose.
__global__ __launch_bounds__(256) void k_prep_w2t(
    const float* __restrict__ W2, u16* __restrict__ W2t) {
  __shared__ float T[32][33];
  const int tx = threadIdx.x & 31, ty0 = threadIdx.x >> 5;
  const int c0 = blockIdx.x * 32, e0 = blockIdx.y * 32, r = blockIdx.z;
#pragma unroll
  for (int rr = 0; rr < 4; ++rr) {
    int e = e0 + ty0 + rr * 8, c = c0 + tx;
    T[ty0 + rr * 8][tx] = (e < 405) ? W2[((size_t)r * 405 + e) * 512 + c] : 0.f;
  }
  __syncthreads();
#pragma unroll
  for (int rr = 0; rr < 4; ++rr) {
    int c = c0 + ty0 + rr * 8, e = e0 + tx;
    W2t[(size_t)c * 1696 + r * 416 + e] = f2bf(T[tx][ty0 + rr * 8]);
  }
}

// ===================== shared MFMA core: 128x64 tile =====================
__device__ __forceinline__ void mfma_block128(
    const u16* __restrict__ Ag, int ldA,
    const u16* __restrict__ Bg, int ldB,
    int nstep, f32x4 (&acc)[4][2]) {
  __shared__ u16 Al[128][40];
  __shared__ u16 Bl[64][40];
  const int tid = threadIdx.x;
  const int lane = tid & 63;
  const int wr = (tid >> 7) & 1, wc = (tid >> 6) & 1;
  const int lrow = lane & 15, lk = (lane >> 4) * 8;

  const int ar0 = tid >> 2;
  const int aseg = (tid & 3) * 8;
  const u16* Ap0 = Ag + (size_t)ar0 * ldA + aseg;
  const u16* Ap1 = Ag + (size_t)(ar0 + 64) * ldA + aseg;
  const u16* Bp  = Bg + (size_t)ar0 * ldB + aseg;

  for (int s = 0; s < nstep; ++s) {
    const int k0 = s * 32;
    u32x4 a0 = *(const u32x4*)(Ap0 + k0);
    u32x4 a1 = *(const u32x4*)(Ap1 + k0);
    u32x4 b0 = *(const u32x4*)(Bp + k0);
    __syncthreads();
    *(u32x4*)&Al[ar0][aseg]      = a0;
    *(u32x4*)&Al[ar0 + 64][aseg] = a1;
    *(u32x4*)&Bl[ar0][aseg]      = b0;
    __syncthreads();
    bf16x8 af[4], bf[2];
#pragma unroll
    for (int fm = 0; fm < 4; ++fm)
      af[fm] = *(const bf16x8*)&Al[wr * 64 + fm * 16 + lrow][lk];
#pragma unroll
    for (int fn = 0; fn < 2; ++fn)
      bf[fn] = *(const bf16x8*)&Bl[wc * 32 + fn * 16 + lrow][lk];
#pragma unroll
    for (int fm = 0; fm < 4; ++fm)
#pragma unroll
      for (int fn = 0; fn < 2; ++fn)
        acc[fm][fn] = __builtin_amdgcn_mfma_f32_16x16x32_bf16(
            af[fm], bf[fn], acc[fm][fn], 0, 0, 0);
  }
}

// ===================== GEMM1 -> qb/kb [bg][t][16], vt [bg][16][512], hbuf =====================
__global__ __launch_bounds__(256) void k_gemm1(
    const u16* __restrict__ xp, const u16* __restrict__ Wt1,
    u16* __restrict__ qb, u16* __restrict__ kb, u16* __restrict__ vt,
    u16* __restrict__ hbuf) {
  f32x4 acc[4][2];
#pragma unroll
  for (int a = 0; a < 4; ++a)
#pragma unroll
    for (int b = 0; b < 2; ++b) acc[a][b] = (f32x4){0.f, 0.f, 0.f, 0.f};
  const int n0 = blockIdx.x * 64, m0 = blockIdx.y * 128;
  mfma_block128(xp + (size_t)m0 * 544, 544, Wt1 + (size_t)n0 * 544, 544, 17, acc);

  const int lane = threadIdx.x & 63;
  const int wr = (threadIdx.x >> 7) & 1, wc = (threadIdx.x >> 6) & 1;
  const int rr = (lane >> 4) * 4, cl = lane & 15;
#pragma unroll
  for (int fm = 0; fm < 4; ++fm) {
#pragma unroll
    for (int i = 0; i < 4; ++i) {
      int m = m0 + wr * 64 + fm * 16 + rr + i;
      int bb = m >> 9, t = m & 511;
#pragma unroll
      for (int fn = 0; fn < 2; ++fn) {
        int c = n0 + wc * 32 + fn * 16 + cl;
        float v = acc[fm][fn][i];
        if (c < 512) {
          qb[((size_t)(((bb << 5) + (c >> 4)) * 512 + t)) * 16 + (c & 15)] = f2bf(v);
        } else if (c < 1024) {
          int q2 = c - 512;
          kb[((size_t)(((bb << 5) + (q2 >> 4)) * 512 + t)) * 16 + (q2 & 15)] = f2bf(v);
        } else if (c < 1536) {
          int q2 = c - 1024;
          vt[((size_t)(((bb << 5) + (q2 >> 4)) * 16 + (q2 & 15))) * 512 + t] = f2bf(v);
        } else {
          int q2 = c - 1536;
          hbuf[(m * 4 + (q2 >> 4)) * 160 + 128 + (q2 & 15)] = f2bf(v);
        }
      }
    }
  }
}

// ===================== attention v2: swapped QK^T via 32x32x16 (K=16 exact) =====================
// S^T = mfma_32x32x16(K_frag, Q_frag): col=q=lane&31, row k=(reg&3)+8*(reg>>2)+4*(lane>>5).
// exp in-reg; per-lane scalar row-sum (+shfl_xor 32); P -> LDS via 4x ds_write_b64;
// PV: 16x16x32 with A=P from LDS, B=V^T from global.
__global__ __launch_bounds__(512) void k_attn(
    const u16* __restrict__ qb, const u16* __restrict__ kb,
    const u16* __restrict__ vt, u16* __restrict__ hbuf) {
  __shared__ u16 P_lds[8][32][40];   // stride 80B: b128-aligned rows, 2-way bank alias only
  const int bg = blockIdx.x, tid = threadIdx.x;
  const int w = tid >> 6, lane = tid & 63;
  const int l31 = lane & 31, hi = lane >> 5;
  const int cl = lane & 15, hq = lane >> 4;
  const int bb = bg >> 5, g = bg & 31, ru = g >> 3, hh = g & 7;
  const u16* qg = qb + (size_t)bg * 512 * 16;
  const u16* kg = kb + (size_t)bg * 512 * 16;
  const u16* vg = vt + (size_t)bg * 16 * 512;
  const f32x16 z16 = {0.f, 0.f, 0.f, 0.f, 0.f, 0.f, 0.f, 0.f,
                      0.f, 0.f, 0.f, 0.f, 0.f, 0.f, 0.f, 0.f};

#pragma unroll
  for (int s = 0; s < 2; ++s) {
    const int q0 = w * 64 + s * 32;
    const int qidx = q0 + l31;
    bf16x8 qf = *(const bf16x8*)(qg + (size_t)qidx * 16 + hi * 8);
    f32x4 oacc[2];
    oacc[0] = (f32x4){0.f, 0.f, 0.f, 0.f};
    oacc[1] = (f32x4){0.f, 0.f, 0.f, 0.f};
    float lsum = 0.f;

    for (int c = 0; c < 16; ++c) {
      bf16x8 kf = *(const bf16x8*)(kg + (size_t)(c * 32 + l31) * 16 + hi * 8);
      f32x16 st = __builtin_amdgcn_mfma_f32_32x32x16_bf16(kf, qf, z16, 0, 0, 0);
      float e[16];
#pragma unroll
      for (int t = 0; t < 16; ++t) e[t] = __expf(st[t]);
      if ((qidx >> 5) == c) {              // diagonal c-tile: mask k==q
        int kl = qidx & 31;
        if (((kl >> 2) & 1) == hi) e[(kl & 3) | ((kl >> 3) << 2)] = 0.f;
      }
#pragma unroll
      for (int t = 0; t < 16; ++t) lsum += e[t];
#pragma unroll
      for (int gg = 0; gg < 4; ++gg) {     // regs 4g..4g+3 -> k = 8g+4hi+0..3
        u32x2 pk;
        pk.x = cvt_pk_bf16(e[4 * gg + 0], e[4 * gg + 1]);
        pk.y = cvt_pk_bf16(e[4 * gg + 2], e[4 * gg + 3]);
        *(u32x2*)&P_lds[w][l31][8 * gg + 4 * hi] = pk;
      }
      // PV for this 32-k tile (per-wave LDS, in-order ds ops -> no barrier needed)
      bf16x8 pa0 = *(const bf16x8*)&P_lds[w][cl][hq * 8];
      bf16x8 pa1 = *(const bf16x8*)&P_lds[w][16 + cl][hq * 8];
      bf16x8 vb = *(const bf16x8*)(vg + (size_t)cl * 512 + c * 32 + hq * 8);
      oacc[0] = __builtin_amdgcn_mfma_f32_16x16x32_bf16(pa0, vb, oacc[0], 0, 0, 0);
      oacc[1] = __builtin_amdgcn_mfma_f32_16x16x32_bf16(pa1, vb, oacc[1], 0, 0, 0);
    }
    float lfull = lsum + __shfl_xor(lsum, 32);   // partner lane holds other k-half of same q
#pragma unroll
    for (int rf = 0; rf < 2; ++rf)
#pragma unroll
      for (int j = 0; j < 4; ++j) {
        int qrow = rf * 16 + hq * 4 + j;
        float denom = __shfl(lfull, qrow);       // lane qrow holds sum for q-row qrow
        int t = q0 + qrow;
        hbuf[((size_t)((bb * 512 + t) * 4 + ru)) * 160 + hh * 16 + cl] =
            f2bf(oacc[rf][j] / denom);
      }
  }
}

// ===================== MLP1: hbuf @ W1t -> h1 (relu, *rs, bf16) =====================
__global__ __launch_bounds__(256) void k_mlp1(
    const u16* __restrict__ hbuf, const u16* __restrict__ W1t,
    const float* __restrict__ rsb, u16* __restrict__ h1) {
  f32x4 acc[4][2];
#pragma unroll
  for (int a = 0; a < 4; ++a)
#pragma unroll
    for (int b = 0; b < 2; ++b) acc[a][b] = (f32x4){0.f, 0.f, 0.f, 0.f};
  const int n0 = blockIdx.x * 64, m0 = blockIdx.y * 128, r = blockIdx.z;
  mfma_block128(hbuf + (size_t)m0 * 640 + r * 160, 640,
                W1t + (size_t)(r * 448 + n0) * 160, 160, 5, acc);

  const int lane = threadIdx.x & 63;
  const int wr = (threadIdx.x >> 7) & 1, wc = (threadIdx.x >> 6) & 1;
  const int rr = (lane >> 4) * 4, cl = lane & 15;
#pragma unroll
  for (int fm = 0; fm < 4; ++fm) {
#pragma unroll
    for (int i = 0; i < 4; ++i) {
      int m = m0 + wr * 64 + fm * 16 + rr + i;
      float rsv = rsb[m * 4 + r];
#pragma unroll
      for (int fn = 0; fn < 2; ++fn) {
        int e = n0 + wc * 32 + fn * 16 + cl;
        if (e < 416)
          h1[(size_t)m * 1696 + r * 416 + e] = f2bf(rsv * fmaxf(acc[fm][fn][i], 0.f));
      }
    }
  }
  if (blockIdx.x == 6 && threadIdx.x < 128) {
    int m = m0 + threadIdx.x;
    h1[(size_t)m * 1696 + 1664 + r] = f2bf(rsb[m * 4 + r]);
    if (r == 0)
      for (int z = 1668; z < 1696; ++z) h1[(size_t)m * 1696 + z] = 0;
  }
}

// ===================== MLP2: h1 @ W2t^T -> y (bias & rs folded) =====================
__global__ __launch_bounds__(256) void k_mlp2(
    const u16* __restrict__ h1, const u16* __restrict__ W2t,
    float* __restrict__ yout) {
  f32x4 acc[4][2];
#pragma unroll
  for (int a = 0; a < 4; ++a)
#pragma unroll
    for (int b = 0; b < 2; ++b) acc[a][b] = (f32x4){0.f, 0.f, 0.f, 0.f};
  const int n0 = blockIdx.x * 64, m0 = blockIdx.y * 128;
  mfma_block128(h1 + (size_t)m0 * 1696, 1696, W2t + (size_t)n0 * 1696, 1696, 53, acc);

  const int lane = threadIdx.x & 63;
  const int wr = (threadIdx.x >> 7) & 1, wc = (threadIdx.x >> 6) & 1;
  const int rr = (lane >> 4) * 4, cl = lane & 15;
#pragma unroll
  for (int fm = 0; fm < 4; ++fm) {
#pragma unroll
    for (int i = 0; i < 4; ++i) {
      int m = m0 + wr * 64 + fm * 16 + rr + i;
#pragma unroll
      for (int fn = 0; fn < 2; ++fn) {
        int c = n0 + wc * 32 + fn * 16 + cl;
        yout[(size_t)m * 512 + c] = acc[fm][fn][i];
      }
    }
  }
}

extern "C" void kernel_launch(void* const* d_in, const int* in_sizes, int n_in,
                              void* d_out, int out_size, void* d_ws, size_t ws_size,
                              hipStream_t stream) {
  const float* x    = (const float*)d_in[0];
  const float* rs   = (const float*)d_in[1];
  const float* Wq   = (const float*)d_in[2];
  const float* bq   = (const float*)d_in[3];
  const float* Wk   = (const float*)d_in[4];
  const float* bk   = (const float*)d_in[5];
  const float* Wv   = (const float*)d_in[6];
  const float* bv   = (const float*)d_in[7];
  const float* Win  = (const float*)d_in[8];
  const float* bin  = (const float*)d_in[9];
  const float* W1   = (const float*)d_in[10];
  const float* b1   = (const float*)d_in[11];
  const float* W2   = (const float*)d_in[12];
  const float* b2   = (const float*)d_in[13];
  float* out = (float*)d_out;

  // ws layout (27.6 MB), all bf16:
  u16* xp   = (u16*)d_ws;             // 2,228,224
  u16* Wt1  = xp + 2228224;           //   870,400
  u16* W1t  = Wt1 + 870400;           //   286,720
  u16* W2t  = W1t + 286720;           //   868,352
  u16* hbuf = W2t + 868352;           // 2,621,440
  u16* qb   = hbuf + 2621440;         // 2,097,152
  u16* kb   = qb + 2097152;           // 2,097,152
  u16* vt   = kb + 2097152;           // 2,097,152
  u16* h1   = qb;                     // 6,946,816 (aliases qb/kb/vt; dead after attn)

  k_prep_misc<<<(MISC_RS + 255) / 256, 256, 0, stream>>>(x, b2, rs, xp, W2t, hbuf, out);
  k_prep_wt1<<<dim3(50, 17), 256, 0, stream>>>(Wq, Wk, Wv, Win, bq, bk, bv, bin, Wt1);
  k_prep_w1t<<<dim3(5, 14, 4), 256, 0, stream>>>(W1, b1, W1t);
  k_prep_w2t<<<dim3(16, 13, 4), 256, 0, stream>>>(W2, W2t);
  k_gemm1<<<dim3(25, 32), 256, 0, stream>>>(xp, Wt1, qb, kb, vt, hbuf);
  k_attn<<<256, 512, 0, stream>>>(qb, kb, vt, hbuf);
  k_mlp1<<<dim3(7, 32, 4), 256, 0, stream>>>(hbuf, W1t, rs, h1);
  k_mlp2<<<dim3(8, 32), 256, 0, stream>>>(h1, W2t, out);
}

// Round 8
// 191.219 us; speedup vs baseline: 3.1708x; 1.0451x over previous
//
#include <hip/hip_runtime.h>

typedef unsigned short u16;
typedef __attribute__((ext_vector_type(8))) short bf16x8;
typedef __attribute__((ext_vector_type(4))) float f32x4;
typedef __attribute__((ext_vector_type(16))) float f32x16;
typedef unsigned int u32;
typedef __attribute__((ext_vector_type(2))) u32 u32x2;
typedef __attribute__((ext_vector_type(4))) u32 u32x4;

__device__ __forceinline__ u16 f2bf(float f) {
  u32 x = __float_as_uint(f);
  return (u16)((x + 0x7fffu + ((x >> 16) & 1u)) >> 16);
}
__device__ __forceinline__ u32 cvt_pk_bf16(float lo, float hi) {
  u32 r;
  asm("v_cvt_pk_bf16_f32 %0, %1, %2" : "=v"(r) : "v"(lo), "v"(hi));
  return r;
}

// ===================== merged prep (1 kernel) =====================
// elementwise segments: y-zero | xp | W2t bias cols | hbuf pad | rs passthrough
#define NZ_Y   2097152
#define N_XP   2228224
#define N_W2B  16384
#define N_HBP  262144
#define N_RS   16384
#define EW_BLOCKS   18048            // (sum of above)/256 exactly
#define WT1_BLOCKS  (52 * 17)        // 1664 cols x 544 rows, 32x32 tiles
#define W1T_BLOCKS  (5 * 14 * 4)     // 160 d x 448 e x 4 rules
#define W2T_BLOCKS  (16 * 13 * 4)    // 512 c x 416 e x 4 rules
#define PREP_BLOCKS (EW_BLOCKS + WT1_BLOCKS + W1T_BLOCKS + W2T_BLOCKS)

__global__ __launch_bounds__(256) void k_prep(
    const float* __restrict__ x, const float* __restrict__ rs,
    const float* __restrict__ Wq, const float* __restrict__ bq,
    const float* __restrict__ Wk, const float* __restrict__ bk,
    const float* __restrict__ Wv, const float* __restrict__ bv,
    const float* __restrict__ Win, const float* __restrict__ bin,
    const float* __restrict__ W1, const float* __restrict__ b1,
    const float* __restrict__ W2, const float* __restrict__ b2,
    u16* __restrict__ xp, u16* __restrict__ Wt1, u16* __restrict__ W1t,
    u16* __restrict__ W2t, u16* __restrict__ hbuf, float* __restrict__ out) {
  __shared__ float T[32][33];
  int b = blockIdx.x;
  if (b < EW_BLOCKS) {
    int i = b * 256 + threadIdx.x;
    if (i < NZ_Y) { out[i] = 0.f; return; }          // zero y (mlp2 atomic-accumulates)
    i -= NZ_Y;
    if (i < N_XP) {
      int m = i / 544, k = i % 544;
      float v = (k < 512) ? x[m * 512 + k] : (k == 512 ? 1.f : 0.f);
      xp[i] = f2bf(v);
      return;
    }
    i -= N_XP;
    if (i < N_W2B) {
      int c = i >> 5, kk = i & 31;
      W2t[(size_t)c * 1696 + 1664 + kk] = (kk < 4) ? f2bf(b2[kk * 512 + c]) : (u16)0;
      return;
    }
    i -= N_W2B;
    if (i < N_HBP) {
      int mr = i >> 4, d = i & 15;
      hbuf[mr * 160 + 144 + d] = f2bf(d == 0 ? 1.f : 0.f);
      return;
    }
    i -= N_HBP;
    out[2097152 + i] = rs[i];
    return;
  }
  b -= EW_BLOCKS;
  const int tx = threadIdx.x & 31, ty0 = threadIdx.x >> 5;
  if (b < WT1_BLOCKS) {
    // Wt1 [1664][544]: [Wq|Wk|Wv|Win]^T, bias row @k=512, q-cols scaled, rows>=1600 zero
    const int c0 = (b % 52) * 32, k0 = (b / 52) * 32;
    const float* W; const float* bias; int ldc, cbase, cmax;
    if (c0 < 512)       { W = Wq;  bias = bq;  ldc = 512; cbase = 0;    cmax = 512; }
    else if (c0 < 1024) { W = Wk;  bias = bk;  ldc = 512; cbase = 512;  cmax = 512; }
    else if (c0 < 1536) { W = Wv;  bias = bv;  ldc = 512; cbase = 1024; cmax = 512; }
    else                { W = Win; bias = bin; ldc = 64;  cbase = 1536; cmax = 64;  }
    const int cc = c0 - cbase + tx;
#pragma unroll
    for (int rr = 0; rr < 4; ++rr) {
      int k = k0 + ty0 + rr * 8;
      float v = 0.f;
      if (cc < cmax) {
        if (k < 512)       v = W[k * ldc + cc];
        else if (k == 512) v = bias[cc];
      }
      T[ty0 + rr * 8][tx] = v;
    }
    __syncthreads();
    const float scale = (c0 < 512) ? 0.25f : 1.f;   // SCALE = HD^-0.5
#pragma unroll
    for (int rr = 0; rr < 4; ++rr) {
      int c = c0 + ty0 + rr * 8, k = k0 + tx;
      Wt1[(size_t)c * 544 + k] = f2bf(T[tx][ty0 + rr * 8] * scale);
    }
    return;
  }
  b -= WT1_BLOCKS;
  if (b < W1T_BLOCKS) {
    // W1t [4][448][160]: W1^T (d<->e), b1 slot @d=144, zero pads
    const int d0 = (b % 5) * 32, e0 = ((b / 5) % 14) * 32, r = b / 70;
#pragma unroll
    for (int rr = 0; rr < 4; ++rr) {
      int d = d0 + ty0 + rr * 8, e = e0 + tx;
      float v = 0.f;
      if (e < 405) {
        if (d < 144)       v = W1[(r * 144 + d) * 405 + e];
        else if (d == 144) v = b1[r * 405 + e];
      }
      T[ty0 + rr * 8][tx] = v;
    }
    __syncthreads();
#pragma unroll
    for (int rr = 0; rr < 4; ++rr) {
      int e = e0 + ty0 + rr * 8, d = d0 + tx;
      W1t[(size_t)r * 71680 + e * 160 + d] = f2bf(T[tx][ty0 + rr * 8]);
    }
    return;
  }
  b -= W1T_BLOCKS;
  {
    // W2t [512][1696]: per-rule W2^T (e<->c), e padded 405->416
    const int c0 = (b % 16) * 32, e0 = ((b / 16) % 13) * 32, r = b / 208;
#pragma unroll
    for (int rr = 0; rr < 4; ++rr) {
      int e = e0 + ty0 + rr * 8, c = c0 + tx;
      T[ty0 + rr * 8][tx] = (e < 405) ? W2[((size_t)r * 405 + e) * 512 + c] : 0.f;
    }
    __syncthreads();
#pragma unroll
    for (int rr = 0; rr < 4; ++rr) {
      int c = c0 + ty0 + rr * 8, e = e0 + tx;
      W2t[(size_t)c * 1696 + r * 416 + e] = f2bf(T[tx][ty0 + rr * 8]);
    }
  }
}

// ===================== MFMA core A: 128x64 tile, 4 waves (2Mx2N) =====================
__device__ __forceinline__ void mfma_block128(
    const u16* __restrict__ Ag, int ldA,
    const u16* __restrict__ Bg, int ldB,
    int nstep, f32x4 (&acc)[4][2]) {
  __shared__ u16 Al[128][40];
  __shared__ u16 Bl[64][40];
  const int tid = threadIdx.x;
  const int lane = tid & 63;
  const int wr = (tid >> 7) & 1, wc = (tid >> 6) & 1;
  const int lrow = lane & 15, lk = (lane >> 4) * 8;

  const int ar0 = tid >> 2;
  const int aseg = (tid & 3) * 8;
  const u16* Ap0 = Ag + (size_t)ar0 * ldA + aseg;
  const u16* Ap1 = Ag + (size_t)(ar0 + 64) * ldA + aseg;
  const u16* Bp  = Bg + (size_t)ar0 * ldB + aseg;

  for (int s = 0; s < nstep; ++s) {
    const int k0 = s * 32;
    u32x4 a0 = *(const u32x4*)(Ap0 + k0);
    u32x4 a1 = *(const u32x4*)(Ap1 + k0);
    u32x4 b0 = *(const u32x4*)(Bp + k0);
    __syncthreads();
    *(u32x4*)&Al[ar0][aseg]      = a0;
    *(u32x4*)&Al[ar0 + 64][aseg] = a1;
    *(u32x4*)&Bl[ar0][aseg]      = b0;
    __syncthreads();
    bf16x8 af[4], bf[2];
#pragma unroll
    for (int fm = 0; fm < 4; ++fm)
      af[fm] = *(const bf16x8*)&Al[wr * 64 + fm * 16 + lrow][lk];
#pragma unroll
    for (int fn = 0; fn < 2; ++fn)
      bf[fn] = *(const bf16x8*)&Bl[wc * 32 + fn * 16 + lrow][lk];
#pragma unroll
    for (int fm = 0; fm < 4; ++fm)
#pragma unroll
      for (int fn = 0; fn < 2; ++fn)
        acc[fm][fn] = __builtin_amdgcn_mfma_f32_16x16x32_bf16(
            af[fm], bf[fn], acc[fm][fn], 0, 0, 0);
  }
}

// ===================== MFMA core B: 128x128 tile, 4 waves (2Mx2N), 4x4 acc =====================
__device__ __forceinline__ void mfma_block_sq(
    const u16* __restrict__ Ag, int ldA,
    const u16* __restrict__ Bg, int ldB,
    int nstep, f32x4 (&acc)[4][4]) {
  __shared__ u16 Al[128][40];
  __shared__ u16 Bl[128][40];
  const int tid = threadIdx.x;
  const int lane = tid & 63;
  const int w = tid >> 6, wr = w >> 1, wc = w & 1;
  const int lrow = lane & 15, lk = (lane >> 4) * 8;

  const int r0 = tid >> 2;
  const int seg = (tid & 3) * 8;
  const u16* Ap0 = Ag + (size_t)r0 * ldA + seg;
  const u16* Ap1 = Ag + (size_t)(r0 + 64) * ldA + seg;
  const u16* Bp0 = Bg + (size_t)r0 * ldB + seg;
  const u16* Bp1 = Bg + (size_t)(r0 + 64) * ldB + seg;

  for (int s = 0; s < nstep; ++s) {
    const int k0 = s * 32;
    u32x4 a0 = *(const u32x4*)(Ap0 + k0);
    u32x4 a1 = *(const u32x4*)(Ap1 + k0);
    u32x4 b0 = *(const u32x4*)(Bp0 + k0);
    u32x4 b1 = *(const u32x4*)(Bp1 + k0);
    __syncthreads();
    *(u32x4*)&Al[r0][seg]      = a0;
    *(u32x4*)&Al[r0 + 64][seg] = a1;
    *(u32x4*)&Bl[r0][seg]      = b0;
    *(u32x4*)&Bl[r0 + 64][seg] = b1;
    __syncthreads();
    bf16x8 af[4], bf[4];
#pragma unroll
    for (int fm = 0; fm < 4; ++fm)
      af[fm] = *(const bf16x8*)&Al[wr * 64 + fm * 16 + lrow][lk];
#pragma unroll
    for (int fn = 0; fn < 4; ++fn)
      bf[fn] = *(const bf16x8*)&Bl[wc * 64 + fn * 16 + lrow][lk];
#pragma unroll
    for (int fm = 0; fm < 4; ++fm)
#pragma unroll
      for (int fn = 0; fn < 4; ++fn)
        acc[fm][fn] = __builtin_amdgcn_mfma_f32_16x16x32_bf16(
            af[fm], bf[fn], acc[fm][fn], 0, 0, 0);
  }
}

// ===================== GEMM1 (128x128): xp @ Wt1^T -> qb/kb/vt/hbuf =====================
__global__ __launch_bounds__(256) void k_gemm1(
    const u16* __restrict__ xp, const u16* __restrict__ Wt1,
    u16* __restrict__ qb, u16* __restrict__ kb, u16* __restrict__ vt,
    u16* __restrict__ hbuf) {
  f32x4 acc[4][4];
#pragma unroll
  for (int a = 0; a < 4; ++a)
#pragma unroll
    for (int b = 0; b < 4; ++b) acc[a][b] = (f32x4){0.f, 0.f, 0.f, 0.f};
  const int n0 = blockIdx.x * 128, m0 = blockIdx.y * 128;
  mfma_block_sq(xp + (size_t)m0 * 544, 544, Wt1 + (size_t)n0 * 544, 544, 17, acc);

  const int lane = threadIdx.x & 63;
  const int w = threadIdx.x >> 6, wr = w >> 1, wc = w & 1;
  const int rr = (lane >> 4) * 4, cl = lane & 15;
#pragma unroll
  for (int fm = 0; fm < 4; ++fm) {
#pragma unroll
    for (int i = 0; i < 4; ++i) {
      int m = m0 + wr * 64 + fm * 16 + rr + i;
      int bb = m >> 9, t = m & 511;
#pragma unroll
      for (int fn = 0; fn < 4; ++fn) {
        int c = n0 + wc * 64 + fn * 16 + cl;
        if (c >= 1600) continue;
        float v = acc[fm][fn][i];
        if (c < 512) {
          qb[((size_t)(((bb << 5) + (c >> 4)) * 512 + t)) * 16 + (c & 15)] = f2bf(v);
        } else if (c < 1024) {
          int q2 = c - 512;
          kb[((size_t)(((bb << 5) + (q2 >> 4)) * 512 + t)) * 16 + (q2 & 15)] = f2bf(v);
        } else if (c < 1536) {
          int q2 = c - 1024;
          vt[((size_t)(((bb << 5) + (q2 >> 4)) * 16 + (q2 & 15))) * 512 + t] = f2bf(v);
        } else {
          int q2 = c - 1536;
          hbuf[(m * 4 + (q2 >> 4)) * 160 + 128 + (q2 & 15)] = f2bf(v);
        }
      }
    }
  }
}

// ===================== attention: swapped QK^T via 32x32x16 (K=16 exact) =====================
__global__ __launch_bounds__(512) void k_attn(
    const u16* __restrict__ qb, const u16* __restrict__ kb,
    const u16* __restrict__ vt, u16* __restrict__ hbuf) {
  __shared__ u16 P_lds[8][32][40];
  const int bg = blockIdx.x, tid = threadIdx.x;
  const int w = tid >> 6, lane = tid & 63;
  const int l31 = lane & 31, hi = lane >> 5;
  const int cl = lane & 15, hq = lane >> 4;
  const int bb = bg >> 5, g = bg & 31, ru = g >> 3, hh = g & 7;
  const u16* qg = qb + (size_t)bg * 512 * 16;
  const u16* kg = kb + (size_t)bg * 512 * 16;
  const u16* vg = vt + (size_t)bg * 16 * 512;
  const f32x16 z16 = {0.f, 0.f, 0.f, 0.f, 0.f, 0.f, 0.f, 0.f,
                      0.f, 0.f, 0.f, 0.f, 0.f, 0.f, 0.f, 0.f};

#pragma unroll
  for (int s = 0; s < 2; ++s) {
    const int q0 = w * 64 + s * 32;
    const int qidx = q0 + l31;
    bf16x8 qf = *(const bf16x8*)(qg + (size_t)qidx * 16 + hi * 8);
    f32x4 oacc[2];
    oacc[0] = (f32x4){0.f, 0.f, 0.f, 0.f};
    oacc[1] = (f32x4){0.f, 0.f, 0.f, 0.f};
    float lsum = 0.f;

    for (int c = 0; c < 16; ++c) {
      bf16x8 kf = *(const bf16x8*)(kg + (size_t)(c * 32 + l31) * 16 + hi * 8);
      f32x16 st = __builtin_amdgcn_mfma_f32_32x32x16_bf16(kf, qf, z16, 0, 0, 0);
      float e[16];
#pragma unroll
      for (int t = 0; t < 16; ++t) e[t] = __expf(st[t]);
      if ((qidx >> 5) == c) {
        int kl = qidx & 31;
        if (((kl >> 2) & 1) == hi) e[(kl & 3) | ((kl >> 3) << 2)] = 0.f;
      }
#pragma unroll
      for (int t = 0; t < 16; ++t) lsum += e[t];
#pragma unroll
      for (int gg = 0; gg < 4; ++gg) {
        u32x2 pk;
        pk.x = cvt_pk_bf16(e[4 * gg + 0], e[4 * gg + 1]);
        pk.y = cvt_pk_bf16(e[4 * gg + 2], e[4 * gg + 3]);
        *(u32x2*)&P_lds[w][l31][8 * gg + 4 * hi] = pk;
      }
      bf16x8 pa0 = *(const bf16x8*)&P_lds[w][cl][hq * 8];
      bf16x8 pa1 = *(const bf16x8*)&P_lds[w][16 + cl][hq * 8];
      bf16x8 vb = *(const bf16x8*)(vg + (size_t)cl * 512 + c * 32 + hq * 8);
      oacc[0] = __builtin_amdgcn_mfma_f32_16x16x32_bf16(pa0, vb, oacc[0], 0, 0, 0);
      oacc[1] = __builtin_amdgcn_mfma_f32_16x16x32_bf16(pa1, vb, oacc[1], 0, 0, 0);
    }
    float lfull = lsum + __shfl_xor(lsum, 32);
#pragma unroll
    for (int rf = 0; rf < 2; ++rf)
#pragma unroll
      for (int j = 0; j < 4; ++j) {
        int qrow = rf * 16 + hq * 4 + j;
        float denom = __shfl(lfull, qrow);
        int t = q0 + qrow;
        hbuf[((size_t)((bb * 512 + t) * 4 + ru)) * 160 + hh * 16 + cl] =
            f2bf(oacc[rf][j] / denom);
      }
  }
}

// ===================== MLP1: hbuf @ W1t -> h1 (relu, *rs, bf16) =====================
__global__ __launch_bounds__(256) void k_mlp1(
    const u16* __restrict__ hbuf, const u16* __restrict__ W1t,
    const float* __restrict__ rsb, u16* __restrict__ h1) {
  f32x4 acc[4][2];
#pragma unroll
  for (int a = 0; a < 4; ++a)
#pragma unroll
    for (int b = 0; b < 2; ++b) acc[a][b] = (f32x4){0.f, 0.f, 0.f, 0.f};
  const int n0 = blockIdx.x * 64, m0 = blockIdx.y * 128, r = blockIdx.z;
  mfma_block128(hbuf + (size_t)m0 * 640 + r * 160, 640,
                W1t + (size_t)(r * 448 + n0) * 160, 160, 5, acc);

  const int lane = threadIdx.x & 63;
  const int wr = (threadIdx.x >> 7) & 1, wc = (threadIdx.x >> 6) & 1;
  const int rr = (lane >> 4) * 4, cl = lane & 15;
#pragma unroll
  for (int fm = 0; fm < 4; ++fm) {
#pragma unroll
    for (int i = 0; i < 4; ++i) {
      int m = m0 + wr * 64 + fm * 16 + rr + i;
      float rsv = rsb[m * 4 + r];
#pragma unroll
      for (int fn = 0; fn < 2; ++fn) {
        int e = n0 + wc * 32 + fn * 16 + cl;
        if (e < 416)
          h1[(size_t)m * 1696 + r * 416 + e] = f2bf(rsv * fmaxf(acc[fm][fn][i], 0.f));
      }
    }
  }
  if (blockIdx.x == 6 && threadIdx.x < 128) {
    int m = m0 + threadIdx.x;
    h1[(size_t)m * 1696 + 1664 + r] = f2bf(rsb[m * 4 + r]);
    if (r == 0)
      for (int z = 1668; z < 1696; ++z) h1[(size_t)m * 1696 + z] = 0;
  }
}

// ===================== MLP2: h1 @ W2t^T -> y, split-K=2, atomic f32 accumulate =====================
__global__ __launch_bounds__(256) void k_mlp2(
    const u16* __restrict__ h1, const u16* __restrict__ W2t,
    float* __restrict__ yout) {
  f32x4 acc[4][2];
#pragma unroll
  for (int a = 0; a < 4; ++a)
#pragma unroll
    for (int b = 0; b < 2; ++b) acc[a][b] = (f32x4){0.f, 0.f, 0.f, 0.f};
  const int n0 = blockIdx.x * 64, m0 = blockIdx.y * 128;
  const int kz = blockIdx.z;
  const int kb0 = kz ? 864 : 0;
  const int ns  = kz ? 26 : 27;      // 27+26 = 53 K-steps of 32 (K=1696)
  mfma_block128(h1 + (size_t)m0 * 1696 + kb0, 1696,
                W2t + (size_t)n0 * 1696 + kb0, 1696, ns, acc);

  const int lane = threadIdx.x & 63;
  const int wr = (threadIdx.x >> 7) & 1, wc = (threadIdx.x >> 6) & 1;
  const int rr = (lane >> 4) * 4, cl = lane & 15;
#pragma unroll
  for (int fm = 0; fm < 4; ++fm) {
#pragma unroll
    for (int i = 0; i < 4; ++i) {
      int m = m0 + wr * 64 + fm * 16 + rr + i;
#pragma unroll
      for (int fn = 0; fn < 2; ++fn) {
        int c = n0 + wc * 32 + fn * 16 + cl;
        unsafeAtomicAdd(&yout[(size_t)m * 512 + c], acc[fm][fn][i]);
      }
    }
  }
}

extern "C" void kernel_launch(void* const* d_in, const int* in_sizes, int n_in,
                              void* d_out, int out_size, void* d_ws, size_t ws_size,
                              hipStream_t stream) {
  const float* x    = (const float*)d_in[0];
  const float* rs   = (const float*)d_in[1];
  const float* Wq   = (const float*)d_in[2];
  const float* bq   = (const float*)d_in[3];
  const float* Wk   = (const float*)d_in[4];
  const float* bk   = (const float*)d_in[5];
  const float* Wv   = (const float*)d_in[6];
  const float* bv   = (const float*)d_in[7];
  const float* Win  = (const float*)d_in[8];
  const float* bin  = (const float*)d_in[9];
  const float* W1   = (const float*)d_in[10];
  const float* b1   = (const float*)d_in[11];
  const float* W2   = (const float*)d_in[12];
  const float* b2   = (const float*)d_in[13];
  float* out = (float*)d_out;

  // ws layout (~27.7 MB), all bf16:
  u16* xp   = (u16*)d_ws;             // 2,228,224   [4096][544]
  u16* Wt1  = xp + 2228224;           //   905,216   [1664][544] (rows>=1600 zero)
  u16* W1t  = Wt1 + 905216;           //   286,720   [4][448][160]
  u16* W2t  = W1t + 286720;           //   868,352   [512][1696]
  u16* hbuf = W2t + 868352;           // 2,621,440   [4096][4][160]
  u16* qb   = hbuf + 2621440;         // 2,097,152
  u16* kb   = qb + 2097152;           // 2,097,152
  u16* vt   = kb + 2097152;           // 2,097,152
  u16* h1   = qb;                     // 6,946,816 (aliases qb/kb/vt + tail; dead after attn)

  k_prep<<<PREP_BLOCKS, 256, 0, stream>>>(x, rs, Wq, bq, Wk, bk, Wv, bv, Win, bin,
                                          W1, b1, W2, b2, xp, Wt1, W1t, W2t, hbuf, out);
  k_gemm1<<<dim3(13, 32), 256, 0, stream>>>(xp, Wt1, qb, kb, vt, hbuf);
  k_attn<<<256, 512, 0, stream>>>(qb, kb, vt, hbuf);
  k_mlp1<<<dim3(7, 32, 4), 256, 0, stream>>>(hbuf, W1t, rs, h1);
  k_mlp2<<<dim3(8, 32, 2), 256, 0, stream>>>(h1, W2t, out);
}

// Round 9
// 184.102 us; speedup vs baseline: 3.2934x; 1.0387x over previous
//
#include <hip/hip_runtime.h>

typedef unsigned short u16;
typedef __attribute__((ext_vector_type(8))) short bf16x8;
typedef __attribute__((ext_vector_type(4))) float f32x4;
typedef __attribute__((ext_vector_type(16))) float f32x16;
typedef unsigned int u32;
typedef __attribute__((ext_vector_type(2))) u32 u32x2;
typedef __attribute__((ext_vector_type(4))) u32 u32x4;

__device__ __forceinline__ u16 f2bf(float f) {
  u32 x = __float_as_uint(f);
  return (u16)((x + 0x7fffu + ((x >> 16) & 1u)) >> 16);
}
__device__ __forceinline__ u32 cvt_pk_bf16(float lo, float hi) {
  u32 r;
  asm("v_cvt_pk_bf16_f32 %0, %1, %2" : "=v"(r) : "v"(lo), "v"(hi));
  return r;
}

// ===================== merged prep (1 kernel) =====================
#define NZ_Y   2097152
#define N_XP   2228224
#define N_W2B  16384
#define N_HBP  262144
#define N_RS   16384
#define EW_BLOCKS   18048
#define WT1_BLOCKS  (52 * 17)
#define W1T_BLOCKS  (5 * 14 * 4)
#define W2T_BLOCKS  (16 * 13 * 4)
#define PREP_BLOCKS (EW_BLOCKS + WT1_BLOCKS + W1T_BLOCKS + W2T_BLOCKS)

__global__ __launch_bounds__(256) void k_prep(
    const float* __restrict__ x, const float* __restrict__ rs,
    const float* __restrict__ Wq, const float* __restrict__ bq,
    const float* __restrict__ Wk, const float* __restrict__ bk,
    const float* __restrict__ Wv, const float* __restrict__ bv,
    const float* __restrict__ Win, const float* __restrict__ bin,
    const float* __restrict__ W1, const float* __restrict__ b1,
    const float* __restrict__ W2, const float* __restrict__ b2,
    u16* __restrict__ xp, u16* __restrict__ Wt1, u16* __restrict__ W1t,
    u16* __restrict__ W2t, u16* __restrict__ hbuf, float* __restrict__ out) {
  __shared__ float T[32][33];
  int b = blockIdx.x;
  if (b < EW_BLOCKS) {
    int i = b * 256 + threadIdx.x;
    if (i < NZ_Y) { out[i] = 0.f; return; }          // zero y (mlp2 atomic-accumulates)
    i -= NZ_Y;
    if (i < N_XP) {
      int m = i / 544, k = i % 544;
      float v = (k < 512) ? x[m * 512 + k] : (k == 512 ? 1.f : 0.f);
      xp[i] = f2bf(v);
      return;
    }
    i -= N_XP;
    if (i < N_W2B) {
      int c = i >> 5, kk = i & 31;
      W2t[(size_t)c * 1696 + 1664 + kk] = (kk < 4) ? f2bf(b2[kk * 512 + c]) : (u16)0;
      return;
    }
    i -= N_W2B;
    if (i < N_HBP) {
      int mr = i >> 4, d = i & 15;
      hbuf[mr * 160 + 144 + d] = f2bf(d == 0 ? 1.f : 0.f);
      return;
    }
    i -= N_HBP;
    out[2097152 + i] = rs[i];
    return;
  }
  b -= EW_BLOCKS;
  const int tx = threadIdx.x & 31, ty0 = threadIdx.x >> 5;
  if (b < WT1_BLOCKS) {
    const int c0 = (b % 52) * 32, k0 = (b / 52) * 32;
    const float* W; const float* bias; int ldc, cbase, cmax;
    if (c0 < 512)       { W = Wq;  bias = bq;  ldc = 512; cbase = 0;    cmax = 512; }
    else if (c0 < 1024) { W = Wk;  bias = bk;  ldc = 512; cbase = 512;  cmax = 512; }
    else if (c0 < 1536) { W = Wv;  bias = bv;  ldc = 512; cbase = 1024; cmax = 512; }
    else                { W = Win; bias = bin; ldc = 64;  cbase = 1536; cmax = 64;  }
    const int cc = c0 - cbase + tx;
#pragma unroll
    for (int rr = 0; rr < 4; ++rr) {
      int k = k0 + ty0 + rr * 8;
      float v = 0.f;
      if (cc < cmax) {
        if (k < 512)       v = W[k * ldc + cc];
        else if (k == 512) v = bias[cc];
      }
      T[ty0 + rr * 8][tx] = v;
    }
    __syncthreads();
    const float scale = (c0 < 512) ? 0.25f : 1.f;   // SCALE = HD^-0.5
#pragma unroll
    for (int rr = 0; rr < 4; ++rr) {
      int c = c0 + ty0 + rr * 8, k = k0 + tx;
      Wt1[(size_t)c * 544 + k] = f2bf(T[tx][ty0 + rr * 8] * scale);
    }
    return;
  }
  b -= WT1_BLOCKS;
  if (b < W1T_BLOCKS) {
    const int d0 = (b % 5) * 32, e0 = ((b / 5) % 14) * 32, r = b / 70;
#pragma unroll
    for (int rr = 0; rr < 4; ++rr) {
      int d = d0 + ty0 + rr * 8, e = e0 + tx;
      float v = 0.f;
      if (e < 405) {
        if (d < 144)       v = W1[(r * 144 + d) * 405 + e];
        else if (d == 144) v = b1[r * 405 + e];
      }
      T[ty0 + rr * 8][tx] = v;
    }
    __syncthreads();
#pragma unroll
    for (int rr = 0; rr < 4; ++rr) {
      int e = e0 + ty0 + rr * 8, d = d0 + tx;
      W1t[(size_t)r * 71680 + e * 160 + d] = f2bf(T[tx][ty0 + rr * 8]);
    }
    return;
  }
  b -= W1T_BLOCKS;
  {
    const int c0 = (b % 16) * 32, e0 = ((b / 16) % 13) * 32, r = b / 208;
#pragma unroll
    for (int rr = 0; rr < 4; ++rr) {
      int e = e0 + ty0 + rr * 8, c = c0 + tx;
      T[ty0 + rr * 8][tx] = (e < 405) ? W2[((size_t)r * 405 + e) * 512 + c] : 0.f;
    }
    __syncthreads();
#pragma unroll
    for (int rr = 0; rr < 4; ++rr) {
      int c = c0 + ty0 + rr * 8, e = e0 + tx;
      W2t[(size_t)c * 1696 + r * 416 + e] = f2bf(T[tx][ty0 + rr * 8]);
    }
  }
}

// ===================== MFMA core A: 128x64 tile, dbuf LDS + reg prefetch =====================
__device__ __forceinline__ void mfma_block128(
    const u16* __restrict__ Ag, int ldA,
    const u16* __restrict__ Bg, int ldB,
    int nstep, f32x4 (&acc)[4][2]) {
  __shared__ u16 Al[2][128][40];
  __shared__ u16 Bl[2][64][40];
  const int tid = threadIdx.x, lane = tid & 63;
  const int wr = (tid >> 7) & 1, wc = (tid >> 6) & 1;
  const int lrow = lane & 15, lk = (lane >> 4) * 8;
  const int ar0 = tid >> 2, aseg = (tid & 3) * 8;
  const u16* Ap0 = Ag + (size_t)ar0 * ldA + aseg;
  const u16* Ap1 = Ag + (size_t)(ar0 + 64) * ldA + aseg;
  const u16* Bp  = Bg + (size_t)ar0 * ldB + aseg;

  u32x4 a0 = *(const u32x4*)(Ap0);
  u32x4 a1 = *(const u32x4*)(Ap1);
  u32x4 b0 = *(const u32x4*)(Bp);
  *(u32x4*)&Al[0][ar0][aseg]      = a0;
  *(u32x4*)&Al[0][ar0 + 64][aseg] = a1;
  *(u32x4*)&Bl[0][ar0][aseg]      = b0;
  __syncthreads();
  int cur = 0;
  for (int s = 0; s < nstep; ++s) {
    const bool more = (s + 1 < nstep);
    if (more) {                         // issue next-step loads BEFORE consuming current
      const int k0 = (s + 1) * 32;
      a0 = *(const u32x4*)(Ap0 + k0);
      a1 = *(const u32x4*)(Ap1 + k0);
      b0 = *(const u32x4*)(Bp + k0);
    }
    bf16x8 af[4], bf[2];
#pragma unroll
    for (int fm = 0; fm < 4; ++fm)
      af[fm] = *(const bf16x8*)&Al[cur][wr * 64 + fm * 16 + lrow][lk];
#pragma unroll
    for (int fn = 0; fn < 2; ++fn)
      bf[fn] = *(const bf16x8*)&Bl[cur][wc * 32 + fn * 16 + lrow][lk];
#pragma unroll
    for (int fm = 0; fm < 4; ++fm)
#pragma unroll
      for (int fn = 0; fn < 2; ++fn)
        acc[fm][fn] = __builtin_amdgcn_mfma_f32_16x16x32_bf16(
            af[fm], bf[fn], acc[fm][fn], 0, 0, 0);
    if (more) {
      *(u32x4*)&Al[cur ^ 1][ar0][aseg]      = a0;
      *(u32x4*)&Al[cur ^ 1][ar0 + 64][aseg] = a1;
      *(u32x4*)&Bl[cur ^ 1][ar0][aseg]      = b0;
      __syncthreads();                  // single barrier per k-step
      cur ^= 1;
    }
  }
}

// ===================== MFMA core B: 128x128 tile, dbuf LDS + reg prefetch =====================
__device__ __forceinline__ void mfma_block_sq(
    const u16* __restrict__ Ag, int ldA,
    const u16* __restrict__ Bg, int ldB,
    int nstep, f32x4 (&acc)[4][4]) {
  __shared__ u16 Al[2][128][40];
  __shared__ u16 Bl[2][128][40];
  const int tid = threadIdx.x, lane = tid & 63;
  const int w = tid >> 6, wr = w >> 1, wc = w & 1;
  const int lrow = lane & 15, lk = (lane >> 4) * 8;
  const int r0 = tid >> 2, seg = (tid & 3) * 8;
  const u16* Ap0 = Ag + (size_t)r0 * ldA + seg;
  const u16* Ap1 = Ag + (size_t)(r0 + 64) * ldA + seg;
  const u16* Bp0 = Bg + (size_t)r0 * ldB + seg;
  const u16* Bp1 = Bg + (size_t)(r0 + 64) * ldB + seg;

  u32x4 a0 = *(const u32x4*)(Ap0);
  u32x4 a1 = *(const u32x4*)(Ap1);
  u32x4 b0 = *(const u32x4*)(Bp0);
  u32x4 b1 = *(const u32x4*)(Bp1);
  *(u32x4*)&Al[0][r0][seg]      = a0;
  *(u32x4*)&Al[0][r0 + 64][seg] = a1;
  *(u32x4*)&Bl[0][r0][seg]      = b0;
  *(u32x4*)&Bl[0][r0 + 64][seg] = b1;
  __syncthreads();
  int cur = 0;
  for (int s = 0; s < nstep; ++s) {
    const bool more = (s + 1 < nstep);
    if (more) {
      const int k0 = (s + 1) * 32;
      a0 = *(const u32x4*)(Ap0 + k0);
      a1 = *(const u32x4*)(Ap1 + k0);
      b0 = *(const u32x4*)(Bp0 + k0);
      b1 = *(const u32x4*)(Bp1 + k0);
    }
    bf16x8 af[4], bf[4];
#pragma unroll
    for (int fm = 0; fm < 4; ++fm)
      af[fm] = *(const bf16x8*)&Al[cur][wr * 64 + fm * 16 + lrow][lk];
#pragma unroll
    for (int fn = 0; fn < 4; ++fn)
      bf[fn] = *(const bf16x8*)&Bl[cur][wc * 64 + fn * 16 + lrow][lk];
#pragma unroll
    for (int fm = 0; fm < 4; ++fm)
#pragma unroll
      for (int fn = 0; fn < 4; ++fn)
        acc[fm][fn] = __builtin_amdgcn_mfma_f32_16x16x32_bf16(
            af[fm], bf[fn], acc[fm][fn], 0, 0, 0);
    if (more) {
      *(u32x4*)&Al[cur ^ 1][r0][seg]      = a0;
      *(u32x4*)&Al[cur ^ 1][r0 + 64][seg] = a1;
      *(u32x4*)&Bl[cur ^ 1][r0][seg]      = b0;
      *(u32x4*)&Bl[cur ^ 1][r0 + 64][seg] = b1;
      __syncthreads();
      cur ^= 1;
    }
  }
}

// ===================== GEMM1 (128x128): xp @ Wt1^T -> qb/kb/vt/hbuf =====================
__global__ __launch_bounds__(256) void k_gemm1(
    const u16* __restrict__ xp, const u16* __restrict__ Wt1,
    u16* __restrict__ qb, u16* __restrict__ kb, u16* __restrict__ vt,
    u16* __restrict__ hbuf) {
  f32x4 acc[4][4];
#pragma unroll
  for (int a = 0; a < 4; ++a)
#pragma unroll
    for (int b = 0; b < 4; ++b) acc[a][b] = (f32x4){0.f, 0.f, 0.f, 0.f};
  const int n0 = blockIdx.x * 128, m0 = blockIdx.y * 128;
  mfma_block_sq(xp + (size_t)m0 * 544, 544, Wt1 + (size_t)n0 * 544, 544, 17, acc);

  const int lane = threadIdx.x & 63;
  const int w = threadIdx.x >> 6, wr = w >> 1, wc = w & 1;
  const int rr = (lane >> 4) * 4, cl = lane & 15;
#pragma unroll
  for (int fm = 0; fm < 4; ++fm) {
#pragma unroll
    for (int i = 0; i < 4; ++i) {
      int m = m0 + wr * 64 + fm * 16 + rr + i;
      int bb = m >> 9, t = m & 511;
#pragma unroll
      for (int fn = 0; fn < 4; ++fn) {
        int c = n0 + wc * 64 + fn * 16 + cl;
        if (c >= 1600) continue;
        float v = acc[fm][fn][i];
        if (c < 512) {
          qb[((size_t)(((bb << 5) + (c >> 4)) * 512 + t)) * 16 + (c & 15)] = f2bf(v);
        } else if (c < 1024) {
          int q2 = c - 512;
          kb[((size_t)(((bb << 5) + (q2 >> 4)) * 512 + t)) * 16 + (q2 & 15)] = f2bf(v);
        } else if (c < 1536) {
          int q2 = c - 1024;
          vt[((size_t)(((bb << 5) + (q2 >> 4)) * 16 + (q2 & 15))) * 512 + t] = f2bf(v);
        } else {
          int q2 = c - 1536;
          hbuf[(m * 4 + (q2 >> 4)) * 160 + 128 + (q2 & 15)] = f2bf(v);
        }
      }
    }
  }
}

// ===================== attention: 2 independent streams, shared kf/vb per c-tile =====================
__global__ __launch_bounds__(512) void k_attn(
    const u16* __restrict__ qb, const u16* __restrict__ kb,
    const u16* __restrict__ vt, u16* __restrict__ hbuf) {
  __shared__ u16 P_lds[8][2][32][40];   // 40 KB: per-wave, per-stream P tile
  const int bg = blockIdx.x, tid = threadIdx.x;
  const int w = tid >> 6, lane = tid & 63;
  const int l31 = lane & 31, hi = lane >> 5;
  const int cl = lane & 15, hq = lane >> 4;
  const int bb = bg >> 5, g = bg & 31, ru = g >> 3, hh = g & 7;
  const u16* qg = qb + (size_t)bg * 512 * 16;
  const u16* kg = kb + (size_t)bg * 512 * 16;
  const u16* vg = vt + (size_t)bg * 16 * 512;
  const f32x16 z16 = {0.f, 0.f, 0.f, 0.f, 0.f, 0.f, 0.f, 0.f,
                      0.f, 0.f, 0.f, 0.f, 0.f, 0.f, 0.f, 0.f};

  bf16x8 qf[2];
  qf[0] = *(const bf16x8*)(qg + (size_t)(w * 64 + l31) * 16 + hi * 8);
  qf[1] = *(const bf16x8*)(qg + (size_t)(w * 64 + 32 + l31) * 16 + hi * 8);
  f32x4 oacc[2][2];
#pragma unroll
  for (int s = 0; s < 2; ++s)
#pragma unroll
    for (int rf = 0; rf < 2; ++rf) oacc[s][rf] = (f32x4){0.f, 0.f, 0.f, 0.f};
  float lsum[2] = {0.f, 0.f};
  // diag mask constants: stream s's 32 q-rows form tile (w*2+s); mask element when c matches
  const int dmask_e = (l31 & 3) | ((l31 >> 3) << 2);
  const bool dmask_on = (((l31 >> 2) & 1) == hi);

  for (int c = 0; c < 16; ++c) {
    bf16x8 kf = *(const bf16x8*)(kg + (size_t)(c * 32 + l31) * 16 + hi * 8);
    bf16x8 vb = *(const bf16x8*)(vg + (size_t)cl * 512 + c * 32 + hq * 8);
    f32x16 st[2];
    st[0] = __builtin_amdgcn_mfma_f32_32x32x16_bf16(kf, qf[0], z16, 0, 0, 0);
    st[1] = __builtin_amdgcn_mfma_f32_32x32x16_bf16(kf, qf[1], z16, 0, 0, 0);
#pragma unroll
    for (int s = 0; s < 2; ++s) {
      float e[16];
#pragma unroll
      for (int t = 0; t < 16; ++t) e[t] = __expf(st[s][t]);
      if (c == w * 2 + s) {             // diagonal sub-tile: mask k==q
        if (dmask_on) e[dmask_e] = 0.f;
      }
      // tree-sum (4-deep) instead of 16-deep serial chain
      float t0 = (e[0] + e[1]) + (e[2] + e[3]);
      float t1 = (e[4] + e[5]) + (e[6] + e[7]);
      float t2 = (e[8] + e[9]) + (e[10] + e[11]);
      float t3 = (e[12] + e[13]) + (e[14] + e[15]);
      lsum[s] += (t0 + t1) + (t2 + t3);
#pragma unroll
      for (int gg = 0; gg < 4; ++gg) {
        u32x2 pk;
        pk.x = cvt_pk_bf16(e[4 * gg + 0], e[4 * gg + 1]);
        pk.y = cvt_pk_bf16(e[4 * gg + 2], e[4 * gg + 3]);
        *(u32x2*)&P_lds[w][s][l31][8 * gg + 4 * hi] = pk;
      }
      bf16x8 pa0 = *(const bf16x8*)&P_lds[w][s][cl][hq * 8];
      bf16x8 pa1 = *(const bf16x8*)&P_lds[w][s][16 + cl][hq * 8];
      oacc[s][0] = __builtin_amdgcn_mfma_f32_16x16x32_bf16(pa0, vb, oacc[s][0], 0, 0, 0);
      oacc[s][1] = __builtin_amdgcn_mfma_f32_16x16x32_bf16(pa1, vb, oacc[s][1], 0, 0, 0);
    }
  }
#pragma unroll
  for (int s = 0; s < 2; ++s) {
    float lfull = lsum[s] + __shfl_xor(lsum[s], 32);
#pragma unroll
    for (int rf = 0; rf < 2; ++rf)
#pragma unroll
      for (int j = 0; j < 4; ++j) {
        int qrow = rf * 16 + hq * 4 + j;
        float denom = __shfl(lfull, qrow);
        int t = w * 64 + s * 32 + qrow;
        hbuf[((size_t)((bb * 512 + t) * 4 + ru)) * 160 + hh * 16 + cl] =
            f2bf(oacc[s][rf][j] / denom);
      }
  }
}

// ===================== MLP1: hbuf @ W1t -> h1 (relu, *rs, bf16) =====================
__global__ __launch_bounds__(256) void k_mlp1(
    const u16* __restrict__ hbuf, const u16* __restrict__ W1t,
    const float* __restrict__ rsb, u16* __restrict__ h1) {
  f32x4 acc[4][2];
#pragma unroll
  for (int a = 0; a < 4; ++a)
#pragma unroll
    for (int b = 0; b < 2; ++b) acc[a][b] = (f32x4){0.f, 0.f, 0.f, 0.f};
  const int n0 = blockIdx.x * 64, m0 = blockIdx.y * 128, r = blockIdx.z;
  mfma_block128(hbuf + (size_t)m0 * 640 + r * 160, 640,
                W1t + (size_t)(r * 448 + n0) * 160, 160, 5, acc);

  const int lane = threadIdx.x & 63;
  const int wr = (threadIdx.x >> 7) & 1, wc = (threadIdx.x >> 6) & 1;
  const int rr = (lane >> 4) * 4, cl = lane & 15;
#pragma unroll
  for (int fm = 0; fm < 4; ++fm) {
#pragma unroll
    for (int i = 0; i < 4; ++i) {
      int m = m0 + wr * 64 + fm * 16 + rr + i;
      float rsv = rsb[m * 4 + r];
#pragma unroll
      for (int fn = 0; fn < 2; ++fn) {
        int e = n0 + wc * 32 + fn * 16 + cl;
        if (e < 416)
          h1[(size_t)m * 1696 + r * 416 + e] = f2bf(rsv * fmaxf(acc[fm][fn][i], 0.f));
      }
    }
  }
  if (blockIdx.x == 6 && threadIdx.x < 128) {
    int m = m0 + threadIdx.x;
    h1[(size_t)m * 1696 + 1664 + r] = f2bf(rsb[m * 4 + r]);
    if (r == 0)
      for (int z = 1668; z < 1696; ++z) h1[(size_t)m * 1696 + z] = 0;
  }
}

// ===================== MLP2: h1 @ W2t^T -> y, split-K=2, atomic f32 accumulate =====================
__global__ __launch_bounds__(256) void k_mlp2(
    const u16* __restrict__ h1, const u16* __restrict__ W2t,
    float* __restrict__ yout) {
  f32x4 acc[4][2];
#pragma unroll
  for (int a = 0; a < 4; ++a)
#pragma unroll
    for (int b = 0; b < 2; ++b) acc[a][b] = (f32x4){0.f, 0.f, 0.f, 0.f};
  const int n0 = blockIdx.x * 64, m0 = blockIdx.y * 128;
  const int kz = blockIdx.z;
  const int kb0 = kz ? 864 : 0;
  const int ns  = kz ? 26 : 27;      // 27+26 = 53 K-steps of 32 (K=1696)
  mfma_block128(h1 + (size_t)m0 * 1696 + kb0, 1696,
                W2t + (size_t)n0 * 1696 + kb0, 1696, ns, acc);

  const int lane = threadIdx.x & 63;
  const int wr = (threadIdx.x >> 7) & 1, wc = (threadIdx.x >> 6) & 1;
  const int rr = (lane >> 4) * 4, cl = lane & 15;
#pragma unroll
  for (int fm = 0; fm < 4; ++fm) {
#pragma unroll
    for (int i = 0; i < 4; ++i) {
      int m = m0 + wr * 64 + fm * 16 + rr + i;
#pragma unroll
      for (int fn = 0; fn < 2; ++fn) {
        int c = n0 + wc * 32 + fn * 16 + cl;
        unsafeAtomicAdd(&yout[(size_t)m * 512 + c], acc[fm][fn][i]);
      }
    }
  }
}

extern "C" void kernel_launch(void* const* d_in, const int* in_sizes, int n_in,
                              void* d_out, int out_size, void* d_ws, size_t ws_size,
                              hipStream_t stream) {
  const float* x    = (const float*)d_in[0];
  const float* rs   = (const float*)d_in[1];
  const float* Wq   = (const float*)d_in[2];
  const float* bq   = (const float*)d_in[3];
  const float* Wk   = (const float*)d_in[4];
  const float* bk   = (const float*)d_in[5];
  const float* Wv   = (const float*)d_in[6];
  const float* bv   = (const float*)d_in[7];
  const float* Win  = (const float*)d_in[8];
  const float* bin  = (const float*)d_in[9];
  const float* W1   = (const float*)d_in[10];
  const float* b1   = (const float*)d_in[11];
  const float* W2   = (const float*)d_in[12];
  const float* b2   = (const float*)d_in[13];
  float* out = (float*)d_out;

  // ws layout (~27.7 MB), all bf16:
  u16* xp   = (u16*)d_ws;             // 2,228,224   [4096][544]
  u16* Wt1  = xp + 2228224;           //   905,216   [1664][544] (rows>=1600 zero)
  u16* W1t  = Wt1 + 905216;           //   286,720   [4][448][160]
  u16* W2t  = W1t + 286720;           //   868,352   [512][1696]
  u16* hbuf = W2t + 868352;           // 2,621,440   [4096][4][160]
  u16* qb   = hbuf + 2621440;         // 2,097,152
  u16* kb   = qb + 2097152;           // 2,097,152
  u16* vt   = kb + 2097152;           // 2,097,152
  u16* h1   = qb;                     // 6,946,816 (aliases qb/kb/vt + tail; dead after attn)

  k_prep<<<PREP_BLOCKS, 256, 0, stream>>>(x, rs, Wq, bq, Wk, bk, Wv, bv, Win, bin,
                                          W1, b1, W2, b2, xp, Wt1, W1t, W2t, hbuf, out);
  k_gemm1<<<dim3(13, 32), 256, 0, stream>>>(xp, Wt1, qb, kb, vt, hbuf);
  k_attn<<<256, 512, 0, stream>>>(qb, kb, vt, hbuf);
  k_mlp1<<<dim3(7, 32, 4), 256, 0, stream>>>(hbuf, W1t, rs, h1);
  k_mlp2<<<dim3(8, 32, 2), 256, 0, stream>>>(h1, W2t, out);
}